// Round 15
// baseline (329.421 us; speedup 1.0000x reference)
//
#include <hip/hip_runtime.h>
#include <hip/hip_bf16.h>

using bf16 = __hip_bfloat16;
typedef float f32x4 __attribute__((ext_vector_type(4)));
typedef short bf16x8 __attribute__((ext_vector_type(8)));

#define DD 768
#define SS 1024
#define HH 12
#define DFF 3072

__device__ __forceinline__ float bf2f(bf16 v) { return __bfloat162float(v); }
__device__ __forceinline__ bf16 f2bf(float v) { return __float2bfloat16(v); }
__device__ __forceinline__ float sb2f(short u) {
  return __uint_as_float(((unsigned)(unsigned short)u) << 16);
}
__device__ __forceinline__ short f2sb(float f) {
  bf16 b = f2bf(f);
  return reinterpret_cast<short&>(b);
}

// async global->LDS, 16B per lane; lds base must be wave-uniform
__device__ __forceinline__ void gld16(const void* g, void* l) {
  __builtin_amdgcn_global_load_lds(
      (const __attribute__((address_space(1))) void*)g,
      (__attribute__((address_space(3))) void*)l, 16, 0, 0);
}

// ---------- transpose + cast f32 -> bf16 : dst[c][r] = src[r][c] ----------
__global__ __launch_bounds__(256) void transpose_cast_kernel(
    const float* __restrict__ src, bf16* __restrict__ dst,
    int R, int C, long sstride, long dstride)
{
  __shared__ float tile[64][65];
  const int c0 = blockIdx.x * 64, r0 = blockIdx.y * 64;
  const float* s = src + (long)blockIdx.z * sstride + (long)r0 * C + c0;
  bf16* d = dst + (long)blockIdx.z * dstride + (long)c0 * R + r0;
  const int rr = threadIdx.x >> 4;
  const int cc = (threadIdx.x & 15) * 4;
  #pragma unroll
  for (int k = 0; k < 4; k++) {
    const f32x4 v = *(const f32x4*)(s + (long)(rr + k * 16) * C + cc);
    *(f32x4*)(&tile[rr + k * 16][cc]) = v;
  }
  __syncthreads();
  #pragma unroll
  for (int k = 0; k < 4; k++) {
    const int c = rr + k * 16;
    short4 pk = make_short4(f2sb(tile[cc + 0][c]), f2sb(tile[cc + 1][c]),
                            f2sb(tile[cc + 2][c]), f2sb(tile[cc + 3][c]));
    *(short4*)(d + (long)c * R + cc) = pk;
  }
}

// ---------- 4x 768x768 transposes (Wq,Wk,Wv,Wo) in one launch ----------
__global__ __launch_bounds__(256) void transpose4_kernel(
    const float* __restrict__ s0, const float* __restrict__ s1,
    const float* __restrict__ s2, const float* __restrict__ s3,
    bf16* __restrict__ dst)
{
  __shared__ float tile[64][65];
  const int z = blockIdx.z;
  const float* src = (z == 0) ? s0 : (z == 1) ? s1 : (z == 2) ? s2 : s3;
  const int c0 = blockIdx.x * 64, r0 = blockIdx.y * 64;
  const float* s = src + (long)r0 * 768 + c0;
  bf16* d = dst + (long)z * 589824 + (long)c0 * 768 + r0;
  const int rr = threadIdx.x >> 4;
  const int cc = (threadIdx.x & 15) * 4;
  #pragma unroll
  for (int k = 0; k < 4; k++) {
    const f32x4 v = *(const f32x4*)(s + (long)(rr + k * 16) * 768 + cc);
    *(f32x4*)(&tile[rr + k * 16][cc]) = v;
  }
  __syncthreads();
  #pragma unroll
  for (int k = 0; k < 4; k++) {
    const int c = rr + k * 16;
    short4 pk = make_short4(f2sb(tile[cc + 0][c]), f2sb(tile[cc + 1][c]),
                            f2sb(tile[cc + 2][c]), f2sb(tile[cc + 3][c]));
    *(short4*)(d + (long)c * 768 + cc) = pk;
  }
}

// ---------- LN1 + pool partials ----------
__global__ __launch_bounds__(256) void ln1pool_kernel(
    const float* __restrict__ x, const float* __restrict__ g,
    const float* __restrict__ b, bf16* __restrict__ out,
    float* __restrict__ pp)
{
  __shared__ float buf[4][768];
  const int w = threadIdx.x >> 6, lane = threadIdx.x & 63;
  const int row = blockIdx.x * 4 + w;
  const float* xr = x + (long)row * DD;
  float v[12];
  float s = 0.f;
  #pragma unroll
  for (int i = 0; i < 12; i++) { v[i] = xr[lane + i * 64]; s += v[i]; }
  #pragma unroll
  for (int o = 1; o < 64; o <<= 1) s += __shfl_xor(s, o, 64);
  const float mu = s * (1.f / DD);
  float vs = 0.f;
  #pragma unroll
  for (int i = 0; i < 12; i++) { const float d = v[i] - mu; vs += d * d; }
  #pragma unroll
  for (int o = 1; o < 64; o <<= 1) vs += __shfl_xor(vs, o, 64);
  const float rstd = rsqrtf(vs * (1.f / DD) + 1e-5f);
  bf16* orow = out + (long)row * DD;
  #pragma unroll
  for (int i = 0; i < 12; i++) {
    const int d = lane + i * 64;
    orow[d] = f2bf((v[i] - mu) * rstd * g[d] + b[d]);
    buf[w][d] = v[i];
  }
  __syncthreads();
  for (int c = threadIdx.x; c < 768; c += 256)
    pp[(long)blockIdx.x * 768 + c] = buf[0][c] + buf[1][c] + buf[2][c] + buf[3][c];
}

// ---------- pool2 ----------
__global__ __launch_bounds__(256) void pool2_kernel(
    const float* __restrict__ pp, float* __restrict__ pooled)
{
  const int idx = blockIdx.x * 256 + threadIdx.x;
  const int bb = idx / 768, d = idx % 768;
  const float* p = pp + (long)bb * 256 * 768 + d;
  float s = 0.f;
  for (int c = 0; c < 256; c++) s += p[(long)c * 768];
  pooled[idx] = s * (1.f / SS);
}

// ---------- routing bias ----------
__global__ __launch_bounds__(256) void route_kernel(
    const float* __restrict__ pooled, const float* __restrict__ Wt,
    const float* __restrict__ bt, float* __restrict__ rbias)
{
  __shared__ float tl[8];
  const int pair = threadIdx.x >> 5, l = threadIdx.x & 31;
  const int b = pair >> 1, j = pair & 1;
  float s = 0.f;
  for (int i = l; i < DD; i += 32) s += pooled[b * DD + i] * Wt[i * 2 + j];
  #pragma unroll
  for (int o = 1; o < 32; o <<= 1) s += __shfl_xor(s, o, 64);
  if (l == 0) tl[pair] = s + bt[j];
  __syncthreads();
  if (threadIdx.x < 16) {
    const int bb = threadIdx.x >> 2, e = threadIdx.x & 3;
    rbias[threadIdx.x] = tl[bb * 2 + (e & 1)];
  }
}

// fast gelu(tanh)
__device__ __forceinline__ float gelu_tanh(float x) {
  const float u = 0.7978845608028654f * (x + 0.044715f * x * x * x);
  const float e = __expf(2.f * u);
  const float t = 1.f - 2.f / (e + 1.f);
  return 0.5f * x * (1.f + t);
}

// ---------- 128x128 bf16 MFMA GEMM (dense modes) ----------
// MODE 0: QKV — Q/K cols -> Cbf (qkv layout), V cols (>=1536) -> Vt transposed
// MODE 1: Cf = aux1 + acc (residual)
template <int MODE>
__global__ __launch_bounds__(256) void gemm128_kernel(
    const bf16* __restrict__ A, const bf16* __restrict__ Bt,
    bf16* __restrict__ Cbf, float* __restrict__ Cf,
    int N, int K, int NT, int GX,
    const float* __restrict__ aux1, bf16* __restrict__ Vt)
{
  __shared__ __align__(16) bf16 As[2][128 * 32];
  __shared__ __align__(16) bf16 Bs[2][128 * 32];

  const int nwg = gridDim.x;
  const int orig = blockIdx.x;
  const int q = nwg >> 3, r = nwg & 7;
  const int xcd = orig & 7, sidx = orig >> 3;
  const int wgid = (xcd < r ? xcd * (q + 1) : r * (q + 1) + (xcd - r) * q) + sidx;

  const int n0 = (wgid % GX) * 128;
  const int m0 = (wgid / GX) * 128;

  const int tid = threadIdx.x;
  const int lane = tid & 63, wv = tid >> 6;
  const int wr = wv >> 1, wc = wv & 1;
  const int lrow = lane & 15, lk = lane >> 4;
  const int lr = lrow, lg = lk;
  const int srow = lane >> 2;
  const int csw = (((lane & 3) ^ ((srow >> 1) & 3)) * 8);

  const bf16* arow[2];
  const bf16* brow[2];
  #pragma unroll
  for (int u = 0; u < 2; u++) {
    const int rbr = u * 64 + wv * 16 + srow;
    arow[u] = A + (long)(m0 + rbr) * K;
    brow[u] = Bt + (long)(n0 + rbr) * K;
  }

  f32x4 acc[4][4] = {};

#define STAGE(T, BUF)                                                   \
  {                                                                     \
    const int k0s = (T) * 32;                                           \
    _Pragma("unroll")                                                   \
    for (int u = 0; u < 2; u++) {                                       \
      const int rb = u * 64 + wv * 16;                                  \
      gld16(arow[u] + k0s + csw, &As[BUF][rb * 32]);                    \
      gld16(brow[u] + k0s + csw, &Bs[BUF][rb * 32]);                    \
    }                                                                   \
  }

  STAGE(0, 0)
  __syncthreads();

  for (int t = 0; t < NT; t++) {
    const int buf = t & 1;
    if (t + 1 < NT) STAGE(t + 1, buf ^ 1)

    bf16x8 af[4], bfr[4];
    #pragma unroll
    for (int i = 0; i < 4; i++) {
      const int ra = wr * 64 + i * 16 + lrow;
      const int rbw = wc * 64 + i * 16 + lrow;
      af[i]  = *(const bf16x8*)(&As[buf][ra * 32 + ((lk ^ ((ra >> 1) & 3)) * 8)]);
      bfr[i] = *(const bf16x8*)(&Bs[buf][rbw * 32 + ((lk ^ ((rbw >> 1) & 3)) * 8)]);
    }
    #pragma unroll
    for (int i = 0; i < 4; i++)
      #pragma unroll
      for (int j = 0; j < 4; j++)
        acc[i][j] = __builtin_amdgcn_mfma_f32_16x16x32_bf16(bfr[j], af[i], acc[i][j], 0, 0, 0);
    __syncthreads();
  }
#undef STAGE

  #pragma unroll
  for (int i = 0; i < 4; i++) {
    const int rloc = wr * 64 + i * 16 + lr;
    #pragma unroll
    for (int j = 0; j < 4; j++) {
      const int col = n0 + wc * 64 + j * 16 + lg * 4;
      const f32x4 v = acc[i][j];
      if (MODE == 0) {
        const int row = m0 + rloc;               // token index
        if (col < 1536) {
          short4 pk = make_short4(f2sb(v[0]), f2sb(v[1]), f2sb(v[2]), f2sb(v[3]));
          *(short4*)(&Cbf[(long)row * N + col]) = pk;
        } else {
          // V: write transposed into vt[(b*12+h)*64+d][s]
          const int c = col - 1536;              // h*64 + d, d 4-aligned
          const int bh64 = (row >> 10) * 768 + c;
          const int s = row & 1023;
          short* vp = (short*)Vt + (long)bh64 * 1024 + s;
          #pragma unroll
          for (int dd = 0; dd < 4; dd++)
            vp[(long)dd * 1024] = f2sb(v[dd]);
        }
      } else {
        const long idx = (long)(m0 + rloc) * N + col;
        const f32x4 xv = *(const f32x4*)(&aux1[idx]);
        f32x4 o = xv + v;
        *(f32x4*)(&Cf[idx]) = o;
      }
    }
  }
}

// ---------- 256x256 MoE GEMM, 8 waves, BK=64, 4-phase counted-vmcnt --------
// MODE 2: segmented up (gathered A, gelu epilogue)
// MODE 3: segmented down split-K x2 (partial slabs)
template <int MODE>
__global__ __launch_bounds__(512, 1) void gemm256p_kernel(
    const bf16* __restrict__ A, const bf16* __restrict__ Bt,
    bf16* __restrict__ Cbf,
    int N, int K, int NT, int GX,
    const float* __restrict__ aux1, const float* __restrict__ gates,
    const int* __restrict__ tokl, const int* __restrict__ cnt_es,
    bf16* __restrict__ yB)
{
  __shared__ __align__(16) bf16 Al[2][256 * 64];
  __shared__ __align__(16) bf16 Bl[2][256 * 64];

  const int nwg = gridDim.x;
  const int orig = blockIdx.x;
  const int q = nwg >> 3, r = nwg & 7;
  const int xcd = orig & 7, sidx = orig >> 3;
  const int wgid = (xcd < r ? xcd * (q + 1) : r * (q + 1) + (xcd - r) * q) + sidx;

  const int n0 = (wgid % GX) * 256;
  int e = 0, g0 = 0, row0 = 0, nval = 0, kseg = 0, kh = 0;
  {
    int p = wgid / GX;
    if (MODE == 3) { kh = p & 1; p >>= 1; }
    int sacc = 0, pacc = 0, found = 0;
    #pragma unroll
    for (int k = 0; k < 8; k++) {
      const int c = cnt_es[k];
      const int pk = (c + 255) >> 8;
      if (!found && p < pacc + pk) {
        found = 1; kseg = k; e = k & 3;
        g0 = (p - pacc) * 256; row0 = sacc + g0; nval = c;
      }
      pacc += pk; sacc += c;
    }
    if (!found) return;
  }
  const int kofs = (MODE == 3) ? kh * 1536 : 0;

  const int tid = threadIdx.x;
  const int lane = tid & 63, wv = tid >> 6;
  const int wr = wv >> 2, wc = wv & 3;
  const int lrow = lane & 15, lk = lane >> 4;
  const int lr = lrow, lg = lk;

  const int strow = tid >> 3;
  const int stch = tid & 7;
  const int ssw = ((stch ^ (strow & 7)) * 8);

  const bf16* Be = Bt + (long)e * N * K;
  const bf16* pA[2][2];
  const bf16* pB[2][2];
  #pragma unroll
  for (int h = 0; h < 2; h++)
    #pragma unroll
    for (int c = 0; c < 2; c++) {
      const int rt = h * 128 + c * 64 + strow;
      if (MODE == 2) {
        const int g = g0 + rt;
        const int tk = (g < nval) ? tokl[kseg * 4096 + g] : tokl[kseg * 4096];
        pA[h][c] = A + (long)tk * K + kofs + ssw;
      } else {
        int rr = row0 + rt; if (rr > 8191) rr = 8191;
        pA[h][c] = A + (long)rr * K + kofs + ssw;
      }
      pB[h][c] = Be + (long)(n0 + rt) * K + kofs + ssw;
    }

#define LDSA(BUF, H, C) (&Al[BUF][(((H) * 128 + (C) * 64 + wv * 8)) * 64])
#define LDSB(BUF, H, C) (&Bl[BUF][(((H) * 128 + (C) * 64 + wv * 8)) * 64])
#define SGA(H, KT, BUF) { gld16(pA[H][0] + (KT) * 64, LDSA(BUF, H, 0)); \
                          gld16(pA[H][1] + (KT) * 64, LDSA(BUF, H, 1)); }
#define SGB(H, KT, BUF) { gld16(pB[H][0] + (KT) * 64, LDSB(BUF, H, 0)); \
                          gld16(pB[H][1] + (KT) * 64, LDSB(BUF, H, 1)); }

  int aoff[2], boff[2];
  #pragma unroll
  for (int ks = 0; ks < 2; ks++) {
    aoff[ks] = (wr * 128 + lrow) * 64 + (((ks * 4 + lk) ^ (lrow & 7)) * 8);
    boff[ks] = (wc * 64 + lrow) * 64 + (((ks * 4 + lk) ^ (lrow & 7)) * 8);
  }

  f32x4 acc[8][4] = {};

  SGA(0, 0, 0) SGA(1, 0, 0)
  SGB(0, 0, 0) SGB(1, 0, 0)
  SGB(0, 1, 1) SGB(1, 1, 1)
  asm volatile("s_waitcnt vmcnt(4)" ::: "memory");
  __builtin_amdgcn_s_barrier();
  __builtin_amdgcn_sched_barrier(0);

  bf16x8 bfr[4][2];

  for (int kt = 0; kt < NT; kt++) {
    const int buf = kt & 1;
    const int ao = buf * 16384, bo = buf * 16384;
    const bool stA = (kt + 1 < NT);
    const bool stB = (kt + 2 < NT);

    #pragma unroll
    for (int ph = 0; ph < 4; ph++) {
      if (ph == 0) { if (stA) SGA(0, kt + 1, buf ^ 1) }
      else if (ph == 1) { if (stA) SGA(1, kt + 1, buf ^ 1) }
      else if (ph == 2) { if (stB) SGB(0, kt + 2, buf) }
      else { if (stB) SGB(1, kt + 2, buf) }

      bf16x8 af[2][2];
      if (ph == 0) {
        #pragma unroll
        for (int j = 0; j < 4; j++)
          #pragma unroll
          for (int ks = 0; ks < 2; ks++)
            bfr[j][ks] = *(const bf16x8*)(&Bl[0][bo + boff[ks] + j * 1024]);
      }
      #pragma unroll
      for (int i2 = 0; i2 < 2; i2++)
        #pragma unroll
        for (int ks = 0; ks < 2; ks++)
          af[i2][ks] = *(const bf16x8*)(&Al[0][ao + aoff[ks] + (ph * 2 + i2) * 1024]);

      asm volatile("s_waitcnt lgkmcnt(0)" ::: "memory");
      __builtin_amdgcn_sched_barrier(0);
      __builtin_amdgcn_s_setprio(1);
      #pragma unroll
      for (int i2 = 0; i2 < 2; i2++)
        #pragma unroll
        for (int j = 0; j < 4; j++)
          #pragma unroll
          for (int ks = 0; ks < 2; ks++)
            acc[ph * 2 + i2][j] = __builtin_amdgcn_mfma_f32_16x16x32_bf16(
                bfr[j][ks], af[i2][ks], acc[ph * 2 + i2][j], 0, 0, 0);
      __builtin_amdgcn_s_setprio(0);
      __builtin_amdgcn_sched_barrier(0);

      if (ph == 3) {
        if (stB) asm volatile("s_waitcnt vmcnt(4)" ::: "memory");
        else     asm volatile("s_waitcnt vmcnt(0)" ::: "memory");
      }
      __builtin_amdgcn_s_barrier();
      __builtin_amdgcn_sched_barrier(0);
    }
  }
#undef SGA
#undef SGB
#undef LDSA
#undef LDSB

  #pragma unroll
  for (int i = 0; i < 8; i++) {
    const int g = g0 + wr * 128 + i * 16 + lr;
    if (g < nval) {
      #pragma unroll
      for (int j = 0; j < 4; j++) {
        const int col = n0 + wc * 64 + j * 16 + lg * 4;
        const f32x4 v = acc[i][j];
        if (MODE == 2) {
          const float* b1e = aux1 + (long)e * N;
          const f32x4 bb = *(const f32x4*)(&b1e[col]);
          short4 pk = make_short4(f2sb(gelu_tanh(v[0] + bb[0])),
                                  f2sb(gelu_tanh(v[1] + bb[1])),
                                  f2sb(gelu_tanh(v[2] + bb[2])),
                                  f2sb(gelu_tanh(v[3] + bb[3])));
          *(short4*)(&Cbf[(long)(row0 - g0 + g) * N + col]) = pk;
        } else {
          const int tk = tokl[kseg * 4096 + g];
          const float gt = gates[tk * 4 + e];
          f32x4 vb = v;
          if (kh == 0) {
            const float* b2e = aux1 + (long)e * N;
            const f32x4 bb = *(const f32x4*)(&b2e[col]);
            vb = v + bb;
          }
          const int pidx = (kseg >> 2) * 2 + kh;
          bf16* yp = (pidx < 3) ? Cbf + (long)pidx * 3145728 : yB;
          short4 pk = make_short4(f2sb(gt * vb[0]), f2sb(gt * vb[1]),
                                  f2sb(gt * vb[2]), f2sb(gt * vb[3]));
          *(short4*)(&yp[(long)tk * 768 + col]) = pk;
        }
      }
    }
  }
}

// ---------- fuse: out += y0+y1+y2+y3 (bf16 partials) ----------
__global__ __launch_bounds__(256) void fuse_kernel(
    const bf16* __restrict__ yA, const bf16* __restrict__ yB,
    float* __restrict__ out)
{
  const long i = ((long)blockIdx.x * 256 + threadIdx.x) * 4;
  const short4 a = *(const short4*)((const short*)yA + i);
  const short4 b = *(const short4*)((const short*)yA + 3145728 + i);
  const short4 c = *(const short4*)((const short*)yA + 6291456 + i);
  const short4 d = *(const short4*)((const short*)yB + i);
  f32x4 o = *(f32x4*)(&out[i]);
  o[0] += sb2f(a.x) + sb2f(b.x) + sb2f(c.x) + sb2f(d.x);
  o[1] += sb2f(a.y) + sb2f(b.y) + sb2f(c.y) + sb2f(d.y);
  o[2] += sb2f(a.z) + sb2f(b.z) + sb2f(c.z) + sb2f(d.z);
  o[3] += sb2f(a.w) + sb2f(b.w) + sb2f(c.w) + sb2f(d.w);
  *(f32x4*)(&out[i]) = o;
}

// ---------- MFMA flash attention: K/V double-buffered, 1 barrier per tile --
__global__ __launch_bounds__(256) void attn_kernel(
    const bf16* __restrict__ qkv, const bf16* __restrict__ vt,
    bf16* __restrict__ ctx)
{
  __shared__ __align__(16) short Qs[64 * 64];
  __shared__ __align__(16) short Ks[2][64 * 64];
  __shared__ __align__(16) short Vts[2][64 * 64];
  __shared__ __align__(16) short Ps[4][16 * 64];

  const int qt = blockIdx.x;
  const int bh = blockIdx.y;
  const int b = bh / HH, h = bh % HH;
  const int tid = threadIdx.x, lane = tid & 63, w = tid >> 6;
  const int lr = lane & 15, lg = lane >> 4;

  const short* kg = (const short*)qkv + ((long)(b * SS)) * 2304 + 768 + h * 64;
  const short* vg = (const short*)vt + ((long)bh * 64) * SS;
  const int sr = lane >> 3, sc = lane & 7;

#define STAGEKV(KT, BUF)                                                   \
  {                                                                        \
    _Pragma("unroll")                                                      \
    for (int c = 0; c < 2; c++) {                                          \
      const int rb = c * 32 + w * 8;                                       \
      const int row = rb + sr;                                             \
      const int ch = sc ^ (row & 7);                                       \
      gld16(kg + ((long)((KT) * 64 + row)) * 2304 + ch * 8, &Ks[BUF][rb * 64]); \
      gld16(vg + ((long)row) * SS + (KT) * 64 + ch * 8, &Vts[BUF][rb * 64]);   \
    }                                                                      \
  }

  // stage Q (scaled) + issue KV(0); one barrier covers both
  const short* qg = (const short*)qkv + ((long)(b * SS + qt * 64)) * 2304 + h * 64;
  #pragma unroll
  for (int i = 0; i < 2; i++) {
    const int idx = i * 256 + tid;
    const int r = idx >> 3, c8 = idx & 7;
    bf16x8 v = *(const bf16x8*)(qg + (long)r * 2304 + c8 * 8);
    bf16x8 o;
    #pragma unroll
    for (int j = 0; j < 8; j++) o[j] = f2sb(sb2f(v[j]) * 0.125f);
    *(bf16x8*)(&Qs[r * 64 + ((c8 ^ (r & 7)) * 8)]) = o;
  }
  STAGEKV(0, 0)
  __syncthreads();

  bf16x8 aq[2];
  {
    const int r = w * 16 + lr;
    aq[0] = *(const bf16x8*)(&Qs[r * 64 + (((lg + 0) ^ (r & 7)) * 8)]);
    aq[1] = *(const bf16x8*)(&Qs[r * 64 + (((lg + 4) ^ (r & 7)) * 8)]);
  }

  float m_run[4], l_run[4];
  f32x4 oacc[4];
  #pragma unroll
  for (int r = 0; r < 4; r++) { m_run[r] = -1e30f; l_run[r] = 0.f; }
  #pragma unroll
  for (int dt = 0; dt < 4; dt++) oacc[dt] = (f32x4){0.f, 0.f, 0.f, 0.f};

  for (int kt = 0; kt < 16; kt++) {
    const int buf = kt & 1;
    if (kt + 1 < 16) STAGEKV(kt + 1, buf ^ 1)

    f32x4 s[4];
    #pragma unroll
    for (int jt = 0; jt < 4; jt++) {
      const int r = jt * 16 + lr;
      bf16x8 bk0 = *(const bf16x8*)(&Ks[buf][r * 64 + (((lg + 0) ^ (r & 7)) * 8)]);
      bf16x8 bk1 = *(const bf16x8*)(&Ks[buf][r * 64 + (((lg + 4) ^ (r & 7)) * 8)]);
      f32x4 a = {};
      a = __builtin_amdgcn_mfma_f32_16x16x32_bf16(aq[0], bk0, a, 0, 0, 0);
      a = __builtin_amdgcn_mfma_f32_16x16x32_bf16(aq[1], bk1, a, 0, 0, 0);
      s[jt] = a;
    }

    #pragma unroll
    for (int r = 0; r < 4; r++) {
      float mt = fmaxf(fmaxf(s[0][r], s[1][r]), fmaxf(s[2][r], s[3][r]));
      mt = fmaxf(mt, __shfl_xor(mt, 1, 64));
      mt = fmaxf(mt, __shfl_xor(mt, 2, 64));
      mt = fmaxf(mt, __shfl_xor(mt, 4, 64));
      mt = fmaxf(mt, __shfl_xor(mt, 8, 64));
      const float mn = fmaxf(m_run[r], mt);
      const float sc0 = __expf(m_run[r] - mn);
      m_run[r] = mn;
      float p0 = __expf(s[0][r] - mn), p1 = __expf(s[1][r] - mn);
      float p2 = __expf(s[2][r] - mn), p3 = __expf(s[3][r] - mn);
      float rs = p0 + p1 + p2 + p3;
      rs += __shfl_xor(rs, 1, 64);
      rs += __shfl_xor(rs, 2, 64);
      rs += __shfl_xor(rs, 4, 64);
      rs += __shfl_xor(rs, 8, 64);
      l_run[r] = l_run[r] * sc0 + rs;
      #pragma unroll
      for (int dt = 0; dt < 4; dt++) oacc[dt][r] *= sc0;
      const int prow = lg * 4 + r;
      const int pswz = (prow & 7) << 3;
      Ps[w][prow * 64 + ((0 * 16 + lr) ^ pswz)] = f2sb(p0);
      Ps[w][prow * 64 + ((1 * 16 + lr) ^ pswz)] = f2sb(p1);
      Ps[w][prow * 64 + ((2 * 16 + lr) ^ pswz)] = f2sb(p2);
      Ps[w][prow * 64 + ((3 * 16 + lr) ^ pswz)] = f2sb(p3);
    }

    bf16x8 pa0 = *(const bf16x8*)(&Ps[w][lr * 64 + (((lg + 0) ^ (lr & 7)) << 3)]);
    bf16x8 pa1 = *(const bf16x8*)(&Ps[w][lr * 64 + (((lg + 4) ^ (lr & 7)) << 3)]);
    #pragma unroll
    for (int dt = 0; dt < 4; dt++) {
      const int r = dt * 16 + lr;
      bf16x8 bv0 = *(const bf16x8*)(&Vts[buf][r * 64 + (((lg + 0) ^ (r & 7)) * 8)]);
      bf16x8 bv1 = *(const bf16x8*)(&Vts[buf][r * 64 + (((lg + 4) ^ (r & 7)) * 8)]);
      oacc[dt] = __builtin_amdgcn_mfma_f32_16x16x32_bf16(pa0, bv0, oacc[dt], 0, 0, 0);
      oacc[dt] = __builtin_amdgcn_mfma_f32_16x16x32_bf16(pa1, bv1, oacc[dt], 0, 0, 0);
    }

    // boundary: drains this iter's prefetch (hidden under compute above)
    __syncthreads();
  }
#undef STAGEKV

  #pragma unroll
  for (int r = 0; r < 4; r++) {
    const float inv = 1.f / l_run[r];
    const long row = (long)(b * SS + qt * 64 + w * 16 + lg * 4 + r);
    #pragma unroll
    for (int dt = 0; dt < 4; dt++)
      ctx[row * DD + h * 64 + dt * 16 + lr] = f2bf(oacc[dt][r] * inv);
  }
}

// ---------- LN2 + gate fused ----------
__global__ __launch_bounds__(256) void lngate_kernel(
    const float* __restrict__ x2, const float* __restrict__ g,
    const float* __restrict__ bln, const float* __restrict__ Wg,
    const float* __restrict__ rbias, bf16* __restrict__ h2,
    float* __restrict__ gates)
{
  const int t = blockIdx.x * 4 + (threadIdx.x >> 6);
  const int lane = threadIdx.x & 63;
  const int b = t >> 10;
  const float* xr = x2 + (long)t * DD;
  float v[12];
  float s = 0.f;
  #pragma unroll
  for (int i = 0; i < 12; i++) { v[i] = xr[lane + i * 64]; s += v[i]; }
  #pragma unroll
  for (int o = 1; o < 64; o <<= 1) s += __shfl_xor(s, o, 64);
  const float mu = s * (1.f / DD);
  float vs = 0.f;
  #pragma unroll
  for (int i = 0; i < 12; i++) { const float d = v[i] - mu; vs += d * d; }
  #pragma unroll
  for (int o = 1; o < 64; o <<= 1) vs += __shfl_xor(vs, o, 64);
  const float rstd = rsqrtf(vs * (1.f / DD) + 1e-5f);
  bf16* orow = h2 + (long)t * DD;
  float a0 = 0.f, a1 = 0.f, a2 = 0.f, a3 = 0.f;
  #pragma unroll
  for (int i = 0; i < 12; i++) {
    const int d = lane + i * 64;
    const float hv = (v[i] - mu) * rstd * g[d] + bln[d];
    orow[d] = f2bf(hv);
    const f32x4 w = *(const f32x4*)(&Wg[d * 4]);
    a0 += hv * w.x; a1 += hv * w.y; a2 += hv * w.z; a3 += hv * w.w;
  }
  #pragma unroll
  for (int o = 1; o < 64; o <<= 1) {
    a0 += __shfl_xor(a0, o, 64); a1 += __shfl_xor(a1, o, 64);
    a2 += __shfl_xor(a2, o, 64); a3 += __shfl_xor(a3, o, 64);
  }
  if (lane == 0) {
    float lg4[4] = { a0 + rbias[b * 4 + 0], a1 + rbias[b * 4 + 1],
                     a2 + rbias[b * 4 + 2], a3 + rbias[b * 4 + 3] };
    int i1 = 0;
    #pragma unroll
    for (int e = 1; e < 4; e++) if (lg4[e] > lg4[i1]) i1 = e;
    int i2 = -1;
    #pragma unroll
    for (int e = 0; e < 4; e++) if (e != i1 && (i2 < 0 || lg4[e] > lg4[i2])) i2 = e;
    const float e2 = __expf(lg4[i2] - lg4[i1]);
    const float den = 1.f + e2;
    float og[4] = {0.f, 0.f, 0.f, 0.f};
    og[i1] = 1.f / den;
    og[i2] = e2 / den;
    *(f32x4*)(&gates[t * 4]) = (f32x4){og[0], og[1], og[2], og[3]};
  }
}

// ---------- scan-based compaction: NO atomics, token-ordered, 1 block -----
__global__ __launch_bounds__(1024) void compact_kernel(
    const float* __restrict__ gates, int* __restrict__ tokl,
    int* __restrict__ cnt)
{
  __shared__ int wtot[8][16];
  const int tid = threadIdx.x;
  const int lane = tid & 63, w = tid >> 6;
  int sA[4], sB[4];
  int lc[8] = {0, 0, 0, 0, 0, 0, 0, 0};
  #pragma unroll
  for (int i = 0; i < 4; i++) {
    const int t = tid * 4 + i;
    const f32x4 g = *(const f32x4*)(&gates[t * 4]);
    int e1 = -1, e2 = -1;
    #pragma unroll
    for (int e = 0; e < 4; e++)
      if (g[e] > 0.f) { if (e1 < 0) e1 = e; else e2 = e; }
    sA[i] = e1; sB[i] = 4 + e2;
    lc[e1]++; lc[4 + e2]++;
  }
  int base[8];
  #pragma unroll
  for (int k = 0; k < 8; k++) {
    int v = lc[k];
    #pragma unroll
    for (int o = 1; o < 64; o <<= 1) {
      const int u = __shfl_up(v, o, 64);
      if (lane >= o) v += u;
    }
    base[k] = v - lc[k];
    if (lane == 63) wtot[k][w] = v;
  }
  __syncthreads();
  #pragma unroll
  for (int k = 0; k < 8; k++) {
    int b = 0;
    for (int ww = 0; ww < 16; ww++)
      if (ww < w) b += wtot[k][ww];
    base[k] += b;
  }
  #pragma unroll
  for (int i = 0; i < 4; i++) {
    const int t = tid * 4 + i;
    tokl[sA[i] * 4096 + base[sA[i]]] = t; base[sA[i]]++;
    tokl[sB[i] * 4096 + base[sB[i]]] = t; base[sB[i]]++;
  }
  if (tid < 8) {
    int s = 0;
    for (int ww = 0; ww < 16; ww++) s += wtot[tid][ww];
    cnt[tid] = s;
  }
}

extern "C" void kernel_launch(void* const* d_in, const int* in_sizes, int n_in,
                              void* d_out, int out_size, void* d_ws, size_t ws_size,
                              hipStream_t stream)
{
  (void)in_sizes; (void)n_in; (void)out_size; (void)ws_size;
  const float* x    = (const float*)d_in[0];
  const float* ln1g = (const float*)d_in[1];
  const float* ln1b = (const float*)d_in[2];
  const float* Wq   = (const float*)d_in[3];
  const float* Wk   = (const float*)d_in[4];
  const float* Wv   = (const float*)d_in[5];
  const float* Wo   = (const float*)d_in[6];
  const float* Wt   = (const float*)d_in[7];
  const float* bt   = (const float*)d_in[8];
  const float* ln2g = (const float*)d_in[9];
  const float* ln2b = (const float*)d_in[10];
  const float* Wg   = (const float*)d_in[11];
  const float* W1   = (const float*)d_in[12];
  const float* b1   = (const float*)d_in[13];
  const float* W2   = (const float*)d_in[14];
  const float* b2   = (const float*)d_in[15];
  float* out = (float*)d_out;

  char* ws = (char*)d_ws;
  bf16*  w1t    = (bf16*)(ws + 0);          // [4][3072][768] bf16 (dead after up)
  bf16*  w2t    = (bf16*)(ws + 18874368);   // [4][768][3072] bf16
  bf16*  h2     = (bf16*)(ws + 37748736);   // [4096][768] bf16 (dead after up)
  float* gates  = (float*)(ws + 44040192);  // [4096][4] f32
  int*   tokl   = (int*)(ws + 44105728);    // [8][4096]
  int*   cnt    = (int*)(ws + 44236800);    // [8]
  float* pooled = (float*)(ws + 44237056);  // [4][768]
  float* rbias  = (float*)(ws + 44249344);  // [4][4]
  bf16*  wqkv_t = (bf16*)(ws + 44249600);   // [2304][768] (Wo tacked after)
  bf16*  h1     = (bf16*)(ws + 48968192);   // [4096][768]
  bf16*  qkv    = (bf16*)(ws + 55259648);   // [4096][2304] (V third unused)
  bf16*  ctx    = (bf16*)(ws + 74134016);   // [4096][768]  (ends 80425472)
  bf16*  vt     = (bf16*)(ws + 80425472);   // [48][64][1024] (ends 86716928)
  bf16*  hid    = (bf16*)(ws + 44249600);   // [8192][3072] (dead zone, MoE time)
  bf16*  wo_t   = wqkv_t + 3 * 589824;
  bf16*  yA     = w1t;                      // 3 partial slabs
  bf16*  yB     = h2;                       // 4th partial slab
  float* pp     = (float*)qkv;              // pool partials (pre-QKV)

  transpose4_kernel<<<dim3(12, 12, 4), 256, 0, stream>>>(Wq, Wk, Wv, Wo, wqkv_t);
  transpose_cast_kernel<<<dim3(48, 12, 4), 256, 0, stream>>>(W1, w1t, 768, 3072, 2359296, 2359296);
  transpose_cast_kernel<<<dim3(12, 48, 4), 256, 0, stream>>>(W2, w2t, 3072, 768, 2359296, 2359296);

  ln1pool_kernel<<<1024, 256, 0, stream>>>(x, ln1g, ln1b, h1, pp);
  pool2_kernel<<<12, 256, 0, stream>>>(pp, pooled);
  route_kernel<<<1, 256, 0, stream>>>(pooled, Wt, bt, rbias);

  // QKV (V written transposed into vt directly)
  gemm128_kernel<0><<<32 * 18, 256, 0, stream>>>(h1, wqkv_t, qkv, nullptr,
                                                 2304, 768, 24, 18, nullptr, vt);
  attn_kernel<<<dim3(16, 48), 256, 0, stream>>>(qkv, vt, ctx);
  gemm128_kernel<1><<<32 * 6, 256, 0, stream>>>(ctx, wo_t, nullptr, out,
                                                768, 768, 24, 6, x, nullptr);
  lngate_kernel<<<1024, 256, 0, stream>>>(out, ln2g, ln2b, Wg, rbias, h2, gates);
  compact_kernel<<<1, 1024, 0, stream>>>(gates, tokl, cnt);

  // up-proj: 256x256, BK=64, 4-phase counted-vmcnt pipeline (NT=12)
  gemm256p_kernel<2><<<40 * 12, 512, 0, stream>>>(h2, w1t, hid,
                                                  3072, 768, 12, 12,
                                                  b1, nullptr, tokl, cnt, nullptr);
  // down-proj: split-K x2, NT=24 per half
  gemm256p_kernel<3><<<40 * 2 * 3, 512, 0, stream>>>(hid, w2t, yA,
                                                     768, 3072, 24, 3,
                                                     b2, gates, tokl, cnt, yB);
  fuse_kernel<<<3072, 256, 0, stream>>>(yA, yB, out);
}

// Round 16
// 314.849 us; speedup vs baseline: 1.0463x; 1.0463x over previous
//
#include <hip/hip_runtime.h>
#include <hip/hip_bf16.h>

using bf16 = __hip_bfloat16;
typedef float f32x4 __attribute__((ext_vector_type(4)));
typedef short bf16x8 __attribute__((ext_vector_type(8)));

#define DD 768
#define SS 1024
#define HH 12
#define DFF 3072

__device__ __forceinline__ float bf2f(bf16 v) { return __bfloat162float(v); }
__device__ __forceinline__ bf16 f2bf(float v) { return __float2bfloat16(v); }
__device__ __forceinline__ float sb2f(short u) {
  return __uint_as_float(((unsigned)(unsigned short)u) << 16);
}
__device__ __forceinline__ short f2sb(float f) {
  bf16 b = f2bf(f);
  return reinterpret_cast<short&>(b);
}

// async global->LDS, 16B per lane; lds base must be wave-uniform
__device__ __forceinline__ void gld16(const void* g, void* l) {
  __builtin_amdgcn_global_load_lds(
      (const __attribute__((address_space(1))) void*)g,
      (__attribute__((address_space(3))) void*)l, 16, 0, 0);
}

// ---------- transpose + cast f32 -> bf16 : dst[c][r] = src[r][c] ----------
__global__ __launch_bounds__(256) void transpose_cast_kernel(
    const float* __restrict__ src, bf16* __restrict__ dst,
    int R, int C, long sstride, long dstride)
{
  __shared__ float tile[64][65];
  const int c0 = blockIdx.x * 64, r0 = blockIdx.y * 64;
  const float* s = src + (long)blockIdx.z * sstride + (long)r0 * C + c0;
  bf16* d = dst + (long)blockIdx.z * dstride + (long)c0 * R + r0;
  const int rr = threadIdx.x >> 4;
  const int cc = (threadIdx.x & 15) * 4;
  #pragma unroll
  for (int k = 0; k < 4; k++) {
    const f32x4 v = *(const f32x4*)(s + (long)(rr + k * 16) * C + cc);
    *(f32x4*)(&tile[rr + k * 16][cc]) = v;
  }
  __syncthreads();
  #pragma unroll
  for (int k = 0; k < 4; k++) {
    const int c = rr + k * 16;
    short4 pk = make_short4(f2sb(tile[cc + 0][c]), f2sb(tile[cc + 1][c]),
                            f2sb(tile[cc + 2][c]), f2sb(tile[cc + 3][c]));
    *(short4*)(d + (long)c * R + cc) = pk;
  }
}

// ---------- 4x 768x768 transposes (Wq,Wk,Wv,Wo) in one launch ----------
__global__ __launch_bounds__(256) void transpose4_kernel(
    const float* __restrict__ s0, const float* __restrict__ s1,
    const float* __restrict__ s2, const float* __restrict__ s3,
    bf16* __restrict__ dst)
{
  __shared__ float tile[64][65];
  const int z = blockIdx.z;
  const float* src = (z == 0) ? s0 : (z == 1) ? s1 : (z == 2) ? s2 : s3;
  const int c0 = blockIdx.x * 64, r0 = blockIdx.y * 64;
  const float* s = src + (long)r0 * 768 + c0;
  bf16* d = dst + (long)z * 589824 + (long)c0 * 768 + r0;
  const int rr = threadIdx.x >> 4;
  const int cc = (threadIdx.x & 15) * 4;
  #pragma unroll
  for (int k = 0; k < 4; k++) {
    const f32x4 v = *(const f32x4*)(s + (long)(rr + k * 16) * 768 + cc);
    *(f32x4*)(&tile[rr + k * 16][cc]) = v;
  }
  __syncthreads();
  #pragma unroll
  for (int k = 0; k < 4; k++) {
    const int c = rr + k * 16;
    short4 pk = make_short4(f2sb(tile[cc + 0][c]), f2sb(tile[cc + 1][c]),
                            f2sb(tile[cc + 2][c]), f2sb(tile[cc + 3][c]));
    *(short4*)(d + (long)c * 768 + cc) = pk;
  }
}

// ---------- LN1 + pool partials ----------
__global__ __launch_bounds__(256) void ln1pool_kernel(
    const float* __restrict__ x, const float* __restrict__ g,
    const float* __restrict__ b, bf16* __restrict__ out,
    float* __restrict__ pp)
{
  __shared__ float buf[4][768];
  const int w = threadIdx.x >> 6, lane = threadIdx.x & 63;
  const int row = blockIdx.x * 4 + w;
  const float* xr = x + (long)row * DD;
  float v[12];
  float s = 0.f;
  #pragma unroll
  for (int i = 0; i < 12; i++) { v[i] = xr[lane + i * 64]; s += v[i]; }
  #pragma unroll
  for (int o = 1; o < 64; o <<= 1) s += __shfl_xor(s, o, 64);
  const float mu = s * (1.f / DD);
  float vs = 0.f;
  #pragma unroll
  for (int i = 0; i < 12; i++) { const float d = v[i] - mu; vs += d * d; }
  #pragma unroll
  for (int o = 1; o < 64; o <<= 1) vs += __shfl_xor(vs, o, 64);
  const float rstd = rsqrtf(vs * (1.f / DD) + 1e-5f);
  bf16* orow = out + (long)row * DD;
  #pragma unroll
  for (int i = 0; i < 12; i++) {
    const int d = lane + i * 64;
    orow[d] = f2bf((v[i] - mu) * rstd * g[d] + b[d]);
    buf[w][d] = v[i];
  }
  __syncthreads();
  for (int c = threadIdx.x; c < 768; c += 256)
    pp[(long)blockIdx.x * 768 + c] = buf[0][c] + buf[1][c] + buf[2][c] + buf[3][c];
}

// ---------- pool2 ----------
__global__ __launch_bounds__(256) void pool2_kernel(
    const float* __restrict__ pp, float* __restrict__ pooled)
{
  const int idx = blockIdx.x * 256 + threadIdx.x;
  const int bb = idx / 768, d = idx % 768;
  const float* p = pp + (long)bb * 256 * 768 + d;
  float s = 0.f;
  for (int c = 0; c < 256; c++) s += p[(long)c * 768];
  pooled[idx] = s * (1.f / SS);
}

// ---------- routing bias ----------
__global__ __launch_bounds__(256) void route_kernel(
    const float* __restrict__ pooled, const float* __restrict__ Wt,
    const float* __restrict__ bt, float* __restrict__ rbias)
{
  __shared__ float tl[8];
  const int pair = threadIdx.x >> 5, l = threadIdx.x & 31;
  const int b = pair >> 1, j = pair & 1;
  float s = 0.f;
  for (int i = l; i < DD; i += 32) s += pooled[b * DD + i] * Wt[i * 2 + j];
  #pragma unroll
  for (int o = 1; o < 32; o <<= 1) s += __shfl_xor(s, o, 64);
  if (l == 0) tl[pair] = s + bt[j];
  __syncthreads();
  if (threadIdx.x < 16) {
    const int bb = threadIdx.x >> 2, e = threadIdx.x & 3;
    rbias[threadIdx.x] = tl[bb * 2 + (e & 1)];
  }
}

// fast gelu(tanh)
__device__ __forceinline__ float gelu_tanh(float x) {
  const float u = 0.7978845608028654f * (x + 0.044715f * x * x * x);
  const float e = __expf(2.f * u);
  const float t = 1.f - 2.f / (e + 1.f);
  return 0.5f * x * (1.f + t);
}

// ---------- 128x128 bf16 MFMA GEMM (dense modes) ----------
// MODE 0: QKV — Q/K cols -> Cbf (qkv layout), V cols (>=1536) -> Vt transposed
// MODE 1: Cf = aux1 + acc (residual)
template <int MODE>
__global__ __launch_bounds__(256) void gemm128_kernel(
    const bf16* __restrict__ A, const bf16* __restrict__ Bt,
    bf16* __restrict__ Cbf, float* __restrict__ Cf,
    int N, int K, int NT, int GX,
    const float* __restrict__ aux1, bf16* __restrict__ Vt)
{
  __shared__ __align__(16) bf16 As[2][128 * 32];
  __shared__ __align__(16) bf16 Bs[2][128 * 32];

  const int nwg = gridDim.x;
  const int orig = blockIdx.x;
  const int q = nwg >> 3, r = nwg & 7;
  const int xcd = orig & 7, sidx = orig >> 3;
  const int wgid = (xcd < r ? xcd * (q + 1) : r * (q + 1) + (xcd - r) * q) + sidx;

  const int n0 = (wgid % GX) * 128;
  const int m0 = (wgid / GX) * 128;

  const int tid = threadIdx.x;
  const int lane = tid & 63, wv = tid >> 6;
  const int wr = wv >> 1, wc = wv & 1;
  const int lrow = lane & 15, lk = lane >> 4;
  const int lr = lrow, lg = lk;
  const int srow = lane >> 2;
  const int csw = (((lane & 3) ^ ((srow >> 1) & 3)) * 8);

  const bf16* arow[2];
  const bf16* brow[2];
  #pragma unroll
  for (int u = 0; u < 2; u++) {
    const int rbr = u * 64 + wv * 16 + srow;
    arow[u] = A + (long)(m0 + rbr) * K;
    brow[u] = Bt + (long)(n0 + rbr) * K;
  }

  f32x4 acc[4][4] = {};

#define STAGE(T, BUF)                                                   \
  {                                                                     \
    const int k0s = (T) * 32;                                           \
    _Pragma("unroll")                                                   \
    for (int u = 0; u < 2; u++) {                                       \
      const int rb = u * 64 + wv * 16;                                  \
      gld16(arow[u] + k0s + csw, &As[BUF][rb * 32]);                    \
      gld16(brow[u] + k0s + csw, &Bs[BUF][rb * 32]);                    \
    }                                                                   \
  }

  STAGE(0, 0)
  __syncthreads();

  for (int t = 0; t < NT; t++) {
    const int buf = t & 1;
    if (t + 1 < NT) STAGE(t + 1, buf ^ 1)

    bf16x8 af[4], bfr[4];
    #pragma unroll
    for (int i = 0; i < 4; i++) {
      const int ra = wr * 64 + i * 16 + lrow;
      const int rbw = wc * 64 + i * 16 + lrow;
      af[i]  = *(const bf16x8*)(&As[buf][ra * 32 + ((lk ^ ((ra >> 1) & 3)) * 8)]);
      bfr[i] = *(const bf16x8*)(&Bs[buf][rbw * 32 + ((lk ^ ((rbw >> 1) & 3)) * 8)]);
    }
    #pragma unroll
    for (int i = 0; i < 4; i++)
      #pragma unroll
      for (int j = 0; j < 4; j++)
        acc[i][j] = __builtin_amdgcn_mfma_f32_16x16x32_bf16(bfr[j], af[i], acc[i][j], 0, 0, 0);
    __syncthreads();
  }
#undef STAGE

  #pragma unroll
  for (int i = 0; i < 4; i++) {
    const int rloc = wr * 64 + i * 16 + lr;
    #pragma unroll
    for (int j = 0; j < 4; j++) {
      const int col = n0 + wc * 64 + j * 16 + lg * 4;
      const f32x4 v = acc[i][j];
      if (MODE == 0) {
        const int row = m0 + rloc;               // token index
        if (col < 1536) {
          short4 pk = make_short4(f2sb(v[0]), f2sb(v[1]), f2sb(v[2]), f2sb(v[3]));
          *(short4*)(&Cbf[(long)row * N + col]) = pk;
        } else {
          // V: write transposed into vt[(b*12+h)*64+d][s]
          const int c = col - 1536;              // h*64 + d, d 4-aligned
          const int bh64 = (row >> 10) * 768 + c;
          const int s = row & 1023;
          short* vp = (short*)Vt + (long)bh64 * 1024 + s;
          #pragma unroll
          for (int dd = 0; dd < 4; dd++)
            vp[(long)dd * 1024] = f2sb(v[dd]);
        }
      } else {
        const long idx = (long)(m0 + rloc) * N + col;
        const f32x4 xv = *(const f32x4*)(&aux1[idx]);
        f32x4 o = xv + v;
        *(f32x4*)(&Cf[idx]) = o;
      }
    }
  }
}

// ---------- 256x256 MoE GEMM, 8 waves, BK=64, 4-phase counted-vmcnt --------
// MODE 2: segmented up (gathered A, gelu epilogue)
// MODE 3: segmented down split-K x2 (partial slabs)
template <int MODE>
__global__ __launch_bounds__(512, 1) void gemm256p_kernel(
    const bf16* __restrict__ A, const bf16* __restrict__ Bt,
    bf16* __restrict__ Cbf,
    int N, int K, int NT, int GX,
    const float* __restrict__ aux1, const float* __restrict__ gates,
    const int* __restrict__ tokl, const int* __restrict__ cnt_es,
    bf16* __restrict__ yB)
{
  __shared__ __align__(16) bf16 Al[2][256 * 64];
  __shared__ __align__(16) bf16 Bl[2][256 * 64];

  const int nwg = gridDim.x;
  const int orig = blockIdx.x;
  const int q = nwg >> 3, r = nwg & 7;
  const int xcd = orig & 7, sidx = orig >> 3;
  const int wgid = (xcd < r ? xcd * (q + 1) : r * (q + 1) + (xcd - r) * q) + sidx;

  const int n0 = (wgid % GX) * 256;
  int e = 0, g0 = 0, row0 = 0, nval = 0, kseg = 0, kh = 0;
  {
    int p = wgid / GX;
    if (MODE == 3) { kh = p & 1; p >>= 1; }
    int sacc = 0, pacc = 0, found = 0;
    #pragma unroll
    for (int k = 0; k < 8; k++) {
      const int c = cnt_es[k];
      const int pk = (c + 255) >> 8;
      if (!found && p < pacc + pk) {
        found = 1; kseg = k; e = k & 3;
        g0 = (p - pacc) * 256; row0 = sacc + g0; nval = c;
      }
      pacc += pk; sacc += c;
    }
    if (!found) return;
  }
  const int kofs = (MODE == 3) ? kh * 1536 : 0;

  const int tid = threadIdx.x;
  const int lane = tid & 63, wv = tid >> 6;
  const int wr = wv >> 2, wc = wv & 3;
  const int lrow = lane & 15, lk = lane >> 4;
  const int lr = lrow, lg = lk;

  const int strow = tid >> 3;
  const int stch = tid & 7;
  const int ssw = ((stch ^ (strow & 7)) * 8);

  const bf16* Be = Bt + (long)e * N * K;
  const bf16* pA[2][2];
  const bf16* pB[2][2];
  #pragma unroll
  for (int h = 0; h < 2; h++)
    #pragma unroll
    for (int c = 0; c < 2; c++) {
      const int rt = h * 128 + c * 64 + strow;
      if (MODE == 2) {
        const int g = g0 + rt;
        const int tk = (g < nval) ? tokl[kseg * 4096 + g] : tokl[kseg * 4096];
        pA[h][c] = A + (long)tk * K + kofs + ssw;
      } else {
        int rr = row0 + rt; if (rr > 8191) rr = 8191;
        pA[h][c] = A + (long)rr * K + kofs + ssw;
      }
      pB[h][c] = Be + (long)(n0 + rt) * K + kofs + ssw;
    }

#define LDSA(BUF, H, C) (&Al[BUF][(((H) * 128 + (C) * 64 + wv * 8)) * 64])
#define LDSB(BUF, H, C) (&Bl[BUF][(((H) * 128 + (C) * 64 + wv * 8)) * 64])
#define SGA(H, KT, BUF) { gld16(pA[H][0] + (KT) * 64, LDSA(BUF, H, 0)); \
                          gld16(pA[H][1] + (KT) * 64, LDSA(BUF, H, 1)); }
#define SGB(H, KT, BUF) { gld16(pB[H][0] + (KT) * 64, LDSB(BUF, H, 0)); \
                          gld16(pB[H][1] + (KT) * 64, LDSB(BUF, H, 1)); }

  int aoff[2], boff[2];
  #pragma unroll
  for (int ks = 0; ks < 2; ks++) {
    aoff[ks] = (wr * 128 + lrow) * 64 + (((ks * 4 + lk) ^ (lrow & 7)) * 8);
    boff[ks] = (wc * 64 + lrow) * 64 + (((ks * 4 + lk) ^ (lrow & 7)) * 8);
  }

  f32x4 acc[8][4] = {};

  SGA(0, 0, 0) SGA(1, 0, 0)
  SGB(0, 0, 0) SGB(1, 0, 0)
  SGB(0, 1, 1) SGB(1, 1, 1)
  asm volatile("s_waitcnt vmcnt(4)" ::: "memory");
  __builtin_amdgcn_s_barrier();
  __builtin_amdgcn_sched_barrier(0);

  bf16x8 bfr[4][2];

  for (int kt = 0; kt < NT; kt++) {
    const int buf = kt & 1;
    const int ao = buf * 16384, bo = buf * 16384;
    const bool stA = (kt + 1 < NT);
    const bool stB = (kt + 2 < NT);

    #pragma unroll
    for (int ph = 0; ph < 4; ph++) {
      if (ph == 0) { if (stA) SGA(0, kt + 1, buf ^ 1) }
      else if (ph == 1) { if (stA) SGA(1, kt + 1, buf ^ 1) }
      else if (ph == 2) { if (stB) SGB(0, kt + 2, buf) }
      else { if (stB) SGB(1, kt + 2, buf) }

      bf16x8 af[2][2];
      if (ph == 0) {
        #pragma unroll
        for (int j = 0; j < 4; j++)
          #pragma unroll
          for (int ks = 0; ks < 2; ks++)
            bfr[j][ks] = *(const bf16x8*)(&Bl[0][bo + boff[ks] + j * 1024]);
      }
      #pragma unroll
      for (int i2 = 0; i2 < 2; i2++)
        #pragma unroll
        for (int ks = 0; ks < 2; ks++)
          af[i2][ks] = *(const bf16x8*)(&Al[0][ao + aoff[ks] + (ph * 2 + i2) * 1024]);

      asm volatile("s_waitcnt lgkmcnt(0)" ::: "memory");
      __builtin_amdgcn_sched_barrier(0);
      __builtin_amdgcn_s_setprio(1);
      #pragma unroll
      for (int i2 = 0; i2 < 2; i2++)
        #pragma unroll
        for (int j = 0; j < 4; j++)
          #pragma unroll
          for (int ks = 0; ks < 2; ks++)
            acc[ph * 2 + i2][j] = __builtin_amdgcn_mfma_f32_16x16x32_bf16(
                bfr[j][ks], af[i2][ks], acc[ph * 2 + i2][j], 0, 0, 0);
      __builtin_amdgcn_s_setprio(0);
      __builtin_amdgcn_sched_barrier(0);

      if (ph == 3) {
        if (stB) asm volatile("s_waitcnt vmcnt(4)" ::: "memory");
        else     asm volatile("s_waitcnt vmcnt(0)" ::: "memory");
      }
      __builtin_amdgcn_s_barrier();
      __builtin_amdgcn_sched_barrier(0);
    }
  }
#undef SGA
#undef SGB
#undef LDSA
#undef LDSB

  #pragma unroll
  for (int i = 0; i < 8; i++) {
    const int g = g0 + wr * 128 + i * 16 + lr;
    if (g < nval) {
      #pragma unroll
      for (int j = 0; j < 4; j++) {
        const int col = n0 + wc * 64 + j * 16 + lg * 4;
        const f32x4 v = acc[i][j];
        if (MODE == 2) {
          const float* b1e = aux1 + (long)e * N;
          const f32x4 bb = *(const f32x4*)(&b1e[col]);
          short4 pk = make_short4(f2sb(gelu_tanh(v[0] + bb[0])),
                                  f2sb(gelu_tanh(v[1] + bb[1])),
                                  f2sb(gelu_tanh(v[2] + bb[2])),
                                  f2sb(gelu_tanh(v[3] + bb[3])));
          *(short4*)(&Cbf[(long)(row0 - g0 + g) * N + col]) = pk;
        } else {
          const int tk = tokl[kseg * 4096 + g];
          const float gt = gates[tk * 4 + e];
          f32x4 vb = v;
          if (kh == 0) {
            const float* b2e = aux1 + (long)e * N;
            const f32x4 bb = *(const f32x4*)(&b2e[col]);
            vb = v + bb;
          }
          const int pidx = (kseg >> 2) * 2 + kh;
          bf16* yp = (pidx < 3) ? Cbf + (long)pidx * 3145728 : yB;
          short4 pk = make_short4(f2sb(gt * vb[0]), f2sb(gt * vb[1]),
                                  f2sb(gt * vb[2]), f2sb(gt * vb[3]));
          *(short4*)(&yp[(long)tk * 768 + col]) = pk;
        }
      }
    }
  }
}

// ---------- fuse: out += y0+y1+y2+y3 (bf16 partials) ----------
__global__ __launch_bounds__(256) void fuse_kernel(
    const bf16* __restrict__ yA, const bf16* __restrict__ yB,
    float* __restrict__ out)
{
  const long i = ((long)blockIdx.x * 256 + threadIdx.x) * 4;
  const short4 a = *(const short4*)((const short*)yA + i);
  const short4 b = *(const short4*)((const short*)yA + 3145728 + i);
  const short4 c = *(const short4*)((const short*)yA + 6291456 + i);
  const short4 d = *(const short4*)((const short*)yB + i);
  f32x4 o = *(f32x4*)(&out[i]);
  o[0] += sb2f(a.x) + sb2f(b.x) + sb2f(c.x) + sb2f(d.x);
  o[1] += sb2f(a.y) + sb2f(b.y) + sb2f(c.y) + sb2f(d.y);
  o[2] += sb2f(a.z) + sb2f(b.z) + sb2f(c.z) + sb2f(d.z);
  o[3] += sb2f(a.w) + sb2f(b.w) + sb2f(c.w) + sb2f(d.w);
  *(f32x4*)(&out[i]) = o;
}

// ---------- MFMA flash attention: 4 waves x 16 q-rows (r14-proven form) ----
__global__ __launch_bounds__(256) void attn_kernel(
    const bf16* __restrict__ qkv, const bf16* __restrict__ vt,
    bf16* __restrict__ ctx)
{
  __shared__ __align__(16) short Qs[64 * 64];
  __shared__ __align__(16) short Ks[64 * 64];
  __shared__ __align__(16) short Vts[64 * 64];
  __shared__ __align__(16) short Ps[4][16 * 64];

  const int qt = blockIdx.x;
  const int bh = blockIdx.y;
  const int b = bh / HH, h = bh % HH;
  const int tid = threadIdx.x, lane = tid & 63, w = tid >> 6;
  const int lr = lane & 15, lg = lane >> 4;

  const short* qg = (const short*)qkv + ((long)(b * SS + qt * 64)) * 2304 + h * 64;
  #pragma unroll
  for (int i = 0; i < 2; i++) {
    const int idx = i * 256 + tid;
    const int r = idx >> 3, c8 = idx & 7;
    bf16x8 v = *(const bf16x8*)(qg + (long)r * 2304 + c8 * 8);
    bf16x8 o;
    #pragma unroll
    for (int j = 0; j < 8; j++) o[j] = f2sb(sb2f(v[j]) * 0.125f);
    *(bf16x8*)(&Qs[r * 64 + ((c8 ^ (r & 7)) * 8)]) = o;
  }
  __syncthreads();

  bf16x8 aq[2];
  {
    const int r = w * 16 + lr;
    aq[0] = *(const bf16x8*)(&Qs[r * 64 + (((lg + 0) ^ (r & 7)) * 8)]);
    aq[1] = *(const bf16x8*)(&Qs[r * 64 + (((lg + 4) ^ (r & 7)) * 8)]);
  }

  float m_run[4], l_run[4];
  f32x4 oacc[4];
  #pragma unroll
  for (int r = 0; r < 4; r++) { m_run[r] = -1e30f; l_run[r] = 0.f; }
  #pragma unroll
  for (int dt = 0; dt < 4; dt++) oacc[dt] = (f32x4){0.f, 0.f, 0.f, 0.f};

  const short* kg = (const short*)qkv + ((long)(b * SS)) * 2304 + 768 + h * 64;
  const short* vg = (const short*)vt + ((long)bh * 64) * SS;
  const int sr = lane >> 3, sc = lane & 7;

  for (int kt = 0; kt < 16; kt++) {
    __syncthreads();
    #pragma unroll
    for (int c = 0; c < 2; c++) {
      const int rb = c * 32 + w * 8;
      const int row = rb + sr;
      const int ch = sc ^ (row & 7);
      gld16(kg + ((long)(kt * 64 + row)) * 2304 + ch * 8, &Ks[rb * 64]);
      gld16(vg + ((long)row) * SS + kt * 64 + ch * 8, &Vts[rb * 64]);
    }
    __syncthreads();

    f32x4 s[4];
    #pragma unroll
    for (int jt = 0; jt < 4; jt++) {
      const int r = jt * 16 + lr;
      bf16x8 bk0 = *(const bf16x8*)(&Ks[r * 64 + (((lg + 0) ^ (r & 7)) * 8)]);
      bf16x8 bk1 = *(const bf16x8*)(&Ks[r * 64 + (((lg + 4) ^ (r & 7)) * 8)]);
      f32x4 a = {};
      a = __builtin_amdgcn_mfma_f32_16x16x32_bf16(aq[0], bk0, a, 0, 0, 0);
      a = __builtin_amdgcn_mfma_f32_16x16x32_bf16(aq[1], bk1, a, 0, 0, 0);
      s[jt] = a;
    }

    #pragma unroll
    for (int r = 0; r < 4; r++) {
      float mt = fmaxf(fmaxf(s[0][r], s[1][r]), fmaxf(s[2][r], s[3][r]));
      mt = fmaxf(mt, __shfl_xor(mt, 1, 64));
      mt = fmaxf(mt, __shfl_xor(mt, 2, 64));
      mt = fmaxf(mt, __shfl_xor(mt, 4, 64));
      mt = fmaxf(mt, __shfl_xor(mt, 8, 64));
      const float mn = fmaxf(m_run[r], mt);
      const float sc0 = __expf(m_run[r] - mn);
      m_run[r] = mn;
      float p0 = __expf(s[0][r] - mn), p1 = __expf(s[1][r] - mn);
      float p2 = __expf(s[2][r] - mn), p3 = __expf(s[3][r] - mn);
      float rs = p0 + p1 + p2 + p3;
      rs += __shfl_xor(rs, 1, 64);
      rs += __shfl_xor(rs, 2, 64);
      rs += __shfl_xor(rs, 4, 64);
      rs += __shfl_xor(rs, 8, 64);
      l_run[r] = l_run[r] * sc0 + rs;
      #pragma unroll
      for (int dt = 0; dt < 4; dt++) oacc[dt][r] *= sc0;
      const int prow = lg * 4 + r;
      const int pswz = (prow & 7) << 3;
      Ps[w][prow * 64 + ((0 * 16 + lr) ^ pswz)] = f2sb(p0);
      Ps[w][prow * 64 + ((1 * 16 + lr) ^ pswz)] = f2sb(p1);
      Ps[w][prow * 64 + ((2 * 16 + lr) ^ pswz)] = f2sb(p2);
      Ps[w][prow * 64 + ((3 * 16 + lr) ^ pswz)] = f2sb(p3);
    }

    bf16x8 pa0 = *(const bf16x8*)(&Ps[w][lr * 64 + (((lg + 0) ^ (lr & 7)) << 3)]);
    bf16x8 pa1 = *(const bf16x8*)(&Ps[w][lr * 64 + (((lg + 4) ^ (lr & 7)) << 3)]);
    #pragma unroll
    for (int dt = 0; dt < 4; dt++) {
      const int r = dt * 16 + lr;
      bf16x8 bv0 = *(const bf16x8*)(&Vts[r * 64 + (((lg + 0) ^ (r & 7)) * 8)]);
      bf16x8 bv1 = *(const bf16x8*)(&Vts[r * 64 + (((lg + 4) ^ (r & 7)) * 8)]);
      oacc[dt] = __builtin_amdgcn_mfma_f32_16x16x32_bf16(pa0, bv0, oacc[dt], 0, 0, 0);
      oacc[dt] = __builtin_amdgcn_mfma_f32_16x16x32_bf16(pa1, bv1, oacc[dt], 0, 0, 0);
    }
  }

  #pragma unroll
  for (int r = 0; r < 4; r++) {
    const float inv = 1.f / l_run[r];
    const long row = (long)(b * SS + qt * 64 + w * 16 + lg * 4 + r);
    #pragma unroll
    for (int dt = 0; dt < 4; dt++)
      ctx[row * DD + h * 64 + dt * 16 + lr] = f2bf(oacc[dt][r] * inv);
  }
}

// ---------- LN2 + gate fused ----------
__global__ __launch_bounds__(256) void lngate_kernel(
    const float* __restrict__ x2, const float* __restrict__ g,
    const float* __restrict__ bln, const float* __restrict__ Wg,
    const float* __restrict__ rbias, bf16* __restrict__ h2,
    float* __restrict__ gates)
{
  const int t = blockIdx.x * 4 + (threadIdx.x >> 6);
  const int lane = threadIdx.x & 63;
  const int b = t >> 10;
  const float* xr = x2 + (long)t * DD;
  float v[12];
  float s = 0.f;
  #pragma unroll
  for (int i = 0; i < 12; i++) { v[i] = xr[lane + i * 64]; s += v[i]; }
  #pragma unroll
  for (int o = 1; o < 64; o <<= 1) s += __shfl_xor(s, o, 64);
  const float mu = s * (1.f / DD);
  float vs = 0.f;
  #pragma unroll
  for (int i = 0; i < 12; i++) { const float d = v[i] - mu; vs += d * d; }
  #pragma unroll
  for (int o = 1; o < 64; o <<= 1) vs += __shfl_xor(vs, o, 64);
  const float rstd = rsqrtf(vs * (1.f / DD) + 1e-5f);
  bf16* orow = h2 + (long)t * DD;
  float a0 = 0.f, a1 = 0.f, a2 = 0.f, a3 = 0.f;
  #pragma unroll
  for (int i = 0; i < 12; i++) {
    const int d = lane + i * 64;
    const float hv = (v[i] - mu) * rstd * g[d] + bln[d];
    orow[d] = f2bf(hv);
    const f32x4 w = *(const f32x4*)(&Wg[d * 4]);
    a0 += hv * w.x; a1 += hv * w.y; a2 += hv * w.z; a3 += hv * w.w;
  }
  #pragma unroll
  for (int o = 1; o < 64; o <<= 1) {
    a0 += __shfl_xor(a0, o, 64); a1 += __shfl_xor(a1, o, 64);
    a2 += __shfl_xor(a2, o, 64); a3 += __shfl_xor(a3, o, 64);
  }
  if (lane == 0) {
    float lg4[4] = { a0 + rbias[b * 4 + 0], a1 + rbias[b * 4 + 1],
                     a2 + rbias[b * 4 + 2], a3 + rbias[b * 4 + 3] };
    int i1 = 0;
    #pragma unroll
    for (int e = 1; e < 4; e++) if (lg4[e] > lg4[i1]) i1 = e;
    int i2 = -1;
    #pragma unroll
    for (int e = 0; e < 4; e++) if (e != i1 && (i2 < 0 || lg4[e] > lg4[i2])) i2 = e;
    const float e2 = __expf(lg4[i2] - lg4[i1]);
    const float den = 1.f + e2;
    float og[4] = {0.f, 0.f, 0.f, 0.f};
    og[i1] = 1.f / den;
    og[i2] = e2 / den;
    *(f32x4*)(&gates[t * 4]) = (f32x4){og[0], og[1], og[2], og[3]};
  }
}

// ---------- scan-based compaction: NO atomics, token-ordered, 1 block -----
__global__ __launch_bounds__(1024) void compact_kernel(
    const float* __restrict__ gates, int* __restrict__ tokl,
    int* __restrict__ cnt)
{
  __shared__ int wtot[8][16];
  const int tid = threadIdx.x;
  const int lane = tid & 63, w = tid >> 6;
  int sA[4], sB[4];
  int lc[8] = {0, 0, 0, 0, 0, 0, 0, 0};
  #pragma unroll
  for (int i = 0; i < 4; i++) {
    const int t = tid * 4 + i;
    const f32x4 g = *(const f32x4*)(&gates[t * 4]);
    int e1 = -1, e2 = -1;
    #pragma unroll
    for (int e = 0; e < 4; e++)
      if (g[e] > 0.f) { if (e1 < 0) e1 = e; else e2 = e; }
    sA[i] = e1; sB[i] = 4 + e2;
    lc[e1]++; lc[4 + e2]++;
  }
  int base[8];
  #pragma unroll
  for (int k = 0; k < 8; k++) {
    int v = lc[k];
    #pragma unroll
    for (int o = 1; o < 64; o <<= 1) {
      const int u = __shfl_up(v, o, 64);
      if (lane >= o) v += u;
    }
    base[k] = v - lc[k];
    if (lane == 63) wtot[k][w] = v;
  }
  __syncthreads();
  #pragma unroll
  for (int k = 0; k < 8; k++) {
    int b = 0;
    for (int ww = 0; ww < 16; ww++)
      if (ww < w) b += wtot[k][ww];
    base[k] += b;
  }
  #pragma unroll
  for (int i = 0; i < 4; i++) {
    const int t = tid * 4 + i;
    tokl[sA[i] * 4096 + base[sA[i]]] = t; base[sA[i]]++;
    tokl[sB[i] * 4096 + base[sB[i]]] = t; base[sB[i]]++;
  }
  if (tid < 8) {
    int s = 0;
    for (int ww = 0; ww < 16; ww++) s += wtot[tid][ww];
    cnt[tid] = s;
  }
}

extern "C" void kernel_launch(void* const* d_in, const int* in_sizes, int n_in,
                              void* d_out, int out_size, void* d_ws, size_t ws_size,
                              hipStream_t stream)
{
  (void)in_sizes; (void)n_in; (void)out_size; (void)ws_size;
  const float* x    = (const float*)d_in[0];
  const float* ln1g = (const float*)d_in[1];
  const float* ln1b = (const float*)d_in[2];
  const float* Wq   = (const float*)d_in[3];
  const float* Wk   = (const float*)d_in[4];
  const float* Wv   = (const float*)d_in[5];
  const float* Wo   = (const float*)d_in[6];
  const float* Wt   = (const float*)d_in[7];
  const float* bt   = (const float*)d_in[8];
  const float* ln2g = (const float*)d_in[9];
  const float* ln2b = (const float*)d_in[10];
  const float* Wg   = (const float*)d_in[11];
  const float* W1   = (const float*)d_in[12];
  const float* b1   = (const float*)d_in[13];
  const float* W2   = (const float*)d_in[14];
  const float* b2   = (const float*)d_in[15];
  float* out = (float*)d_out;

  char* ws = (char*)d_ws;
  bf16*  w1t    = (bf16*)(ws + 0);          // [4][3072][768] bf16 (dead after up)
  bf16*  w2t    = (bf16*)(ws + 18874368);   // [4][768][3072] bf16
  bf16*  h2     = (bf16*)(ws + 37748736);   // [4096][768] bf16 (dead after up)
  float* gates  = (float*)(ws + 44040192);  // [4096][4] f32
  int*   tokl   = (int*)(ws + 44105728);    // [8][4096]
  int*   cnt    = (int*)(ws + 44236800);    // [8]
  float* pooled = (float*)(ws + 44237056);  // [4][768]
  float* rbias  = (float*)(ws + 44249344);  // [4][4]
  bf16*  wqkv_t = (bf16*)(ws + 44249600);   // [2304][768] (Wo tacked after)
  bf16*  h1     = (bf16*)(ws + 48968192);   // [4096][768]
  bf16*  qkv    = (bf16*)(ws + 55259648);   // [4096][2304] (V third unused)
  bf16*  ctx    = (bf16*)(ws + 74134016);   // [4096][768]  (ends 80425472)
  bf16*  vt     = (bf16*)(ws + 80425472);   // [48][64][1024] (ends 86716928)
  bf16*  hid    = (bf16*)(ws + 44249600);   // [8192][3072] (dead zone, MoE time)
  bf16*  wo_t   = wqkv_t + 3 * 589824;
  bf16*  yA     = w1t;                      // 3 partial slabs
  bf16*  yB     = h2;                       // 4th partial slab
  float* pp     = (float*)qkv;              // pool partials (pre-QKV)

  transpose4_kernel<<<dim3(12, 12, 4), 256, 0, stream>>>(Wq, Wk, Wv, Wo, wqkv_t);
  transpose_cast_kernel<<<dim3(48, 12, 4), 256, 0, stream>>>(W1, w1t, 768, 3072, 2359296, 2359296);
  transpose_cast_kernel<<<dim3(12, 48, 4), 256, 0, stream>>>(W2, w2t, 3072, 768, 2359296, 2359296);

  ln1pool_kernel<<<1024, 256, 0, stream>>>(x, ln1g, ln1b, h1, pp);
  pool2_kernel<<<12, 256, 0, stream>>>(pp, pooled);
  route_kernel<<<1, 256, 0, stream>>>(pooled, Wt, bt, rbias);

  // QKV (V written transposed into vt directly)
  gemm128_kernel<0><<<32 * 18, 256, 0, stream>>>(h1, wqkv_t, qkv, nullptr,
                                                 2304, 768, 24, 18, nullptr, vt);
  attn_kernel<<<dim3(16, 48), 256, 0, stream>>>(qkv, vt, ctx);
  gemm128_kernel<1><<<32 * 6, 256, 0, stream>>>(ctx, wo_t, nullptr, out,
                                                768, 768, 24, 6, x, nullptr);
  lngate_kernel<<<1024, 256, 0, stream>>>(out, ln2g, ln2b, Wg, rbias, h2, gates);
  compact_kernel<<<1, 1024, 0, stream>>>(gates, tokl, cnt);

  // up-proj: 256x256, BK=64, 4-phase counted-vmcnt pipeline (NT=12)
  gemm256p_kernel<2><<<40 * 12, 512, 0, stream>>>(h2, w1t, hid,
                                                  3072, 768, 12, 12,
                                                  b1, nullptr, tokl, cnt, nullptr);
  // down-proj: split-K x2, NT=24 per half
  gemm256p_kernel<3><<<40 * 2 * 3, 512, 0, stream>>>(hid, w2t, yA,
                                                     768, 3072, 24, 3,
                                                     b2, gates, tokl, cnt, yB);
  fuse_kernel<<<3072, 256, 0, stream>>>(yA, yB, out);
}

// Round 17
// 310.635 us; speedup vs baseline: 1.0605x; 1.0136x over previous
//
#include <hip/hip_runtime.h>
#include <hip/hip_bf16.h>

using bf16 = __hip_bfloat16;
typedef float f32x4 __attribute__((ext_vector_type(4)));
typedef short bf16x8 __attribute__((ext_vector_type(8)));

#define DD 768
#define SS 1024
#define HH 12
#define DFF 3072

__device__ __forceinline__ float bf2f(bf16 v) { return __bfloat162float(v); }
__device__ __forceinline__ bf16 f2bf(float v) { return __float2bfloat16(v); }
__device__ __forceinline__ float sb2f(short u) {
  return __uint_as_float(((unsigned)(unsigned short)u) << 16);
}
__device__ __forceinline__ short f2sb(float f) {
  bf16 b = f2bf(f);
  return reinterpret_cast<short&>(b);
}

// async global->LDS, 16B per lane; lds base must be wave-uniform
__device__ __forceinline__ void gld16(const void* g, void* l) {
  __builtin_amdgcn_global_load_lds(
      (const __attribute__((address_space(1))) void*)g,
      (__attribute__((address_space(3))) void*)l, 16, 0, 0);
}

// ---------- transpose + cast f32 -> bf16 : dst[c][r] = src[r][c] ----------
__global__ __launch_bounds__(256) void transpose_cast_kernel(
    const float* __restrict__ src, bf16* __restrict__ dst,
    int R, int C, long sstride, long dstride)
{
  __shared__ float tile[64][65];
  const int c0 = blockIdx.x * 64, r0 = blockIdx.y * 64;
  const float* s = src + (long)blockIdx.z * sstride + (long)r0 * C + c0;
  bf16* d = dst + (long)blockIdx.z * dstride + (long)c0 * R + r0;
  const int rr = threadIdx.x >> 4;
  const int cc = (threadIdx.x & 15) * 4;
  #pragma unroll
  for (int k = 0; k < 4; k++) {
    const f32x4 v = *(const f32x4*)(s + (long)(rr + k * 16) * C + cc);
    *(f32x4*)(&tile[rr + k * 16][cc]) = v;
  }
  __syncthreads();
  #pragma unroll
  for (int k = 0; k < 4; k++) {
    const int c = rr + k * 16;
    short4 pk = make_short4(f2sb(tile[cc + 0][c]), f2sb(tile[cc + 1][c]),
                            f2sb(tile[cc + 2][c]), f2sb(tile[cc + 3][c]));
    *(short4*)(d + (long)c * R + cc) = pk;
  }
}

// ---------- 4x 768x768 transposes (Wq,Wk,Wv,Wo) in one launch ----------
__global__ __launch_bounds__(256) void transpose4_kernel(
    const float* __restrict__ s0, const float* __restrict__ s1,
    const float* __restrict__ s2, const float* __restrict__ s3,
    bf16* __restrict__ dst)
{
  __shared__ float tile[64][65];
  const int z = blockIdx.z;
  const float* src = (z == 0) ? s0 : (z == 1) ? s1 : (z == 2) ? s2 : s3;
  const int c0 = blockIdx.x * 64, r0 = blockIdx.y * 64;
  const float* s = src + (long)r0 * 768 + c0;
  bf16* d = dst + (long)z * 589824 + (long)c0 * 768 + r0;
  const int rr = threadIdx.x >> 4;
  const int cc = (threadIdx.x & 15) * 4;
  #pragma unroll
  for (int k = 0; k < 4; k++) {
    const f32x4 v = *(const f32x4*)(s + (long)(rr + k * 16) * 768 + cc);
    *(f32x4*)(&tile[rr + k * 16][cc]) = v;
  }
  __syncthreads();
  #pragma unroll
  for (int k = 0; k < 4; k++) {
    const int c = rr + k * 16;
    short4 pk = make_short4(f2sb(tile[cc + 0][c]), f2sb(tile[cc + 1][c]),
                            f2sb(tile[cc + 2][c]), f2sb(tile[cc + 3][c]));
    *(short4*)(d + (long)c * 768 + cc) = pk;
  }
}

// ---------- LN1 + pool partials ----------
__global__ __launch_bounds__(256) void ln1pool_kernel(
    const float* __restrict__ x, const float* __restrict__ g,
    const float* __restrict__ b, bf16* __restrict__ out,
    float* __restrict__ pp)
{
  __shared__ float buf[4][768];
  const int w = threadIdx.x >> 6, lane = threadIdx.x & 63;
  const int row = blockIdx.x * 4 + w;
  const float* xr = x + (long)row * DD;
  float v[12];
  float s = 0.f;
  #pragma unroll
  for (int i = 0; i < 12; i++) { v[i] = xr[lane + i * 64]; s += v[i]; }
  #pragma unroll
  for (int o = 1; o < 64; o <<= 1) s += __shfl_xor(s, o, 64);
  const float mu = s * (1.f / DD);
  float vs = 0.f;
  #pragma unroll
  for (int i = 0; i < 12; i++) { const float d = v[i] - mu; vs += d * d; }
  #pragma unroll
  for (int o = 1; o < 64; o <<= 1) vs += __shfl_xor(vs, o, 64);
  const float rstd = rsqrtf(vs * (1.f / DD) + 1e-5f);
  bf16* orow = out + (long)row * DD;
  #pragma unroll
  for (int i = 0; i < 12; i++) {
    const int d = lane + i * 64;
    orow[d] = f2bf((v[i] - mu) * rstd * g[d] + b[d]);
    buf[w][d] = v[i];
  }
  __syncthreads();
  for (int c = threadIdx.x; c < 768; c += 256)
    pp[(long)blockIdx.x * 768 + c] = buf[0][c] + buf[1][c] + buf[2][c] + buf[3][c];
}

// ---------- pool2 ----------
__global__ __launch_bounds__(256) void pool2_kernel(
    const float* __restrict__ pp, float* __restrict__ pooled)
{
  const int idx = blockIdx.x * 256 + threadIdx.x;
  const int bb = idx / 768, d = idx % 768;
  const float* p = pp + (long)bb * 256 * 768 + d;
  float s = 0.f;
  for (int c = 0; c < 256; c++) s += p[(long)c * 768];
  pooled[idx] = s * (1.f / SS);
}

// ---------- routing bias ----------
__global__ __launch_bounds__(256) void route_kernel(
    const float* __restrict__ pooled, const float* __restrict__ Wt,
    const float* __restrict__ bt, float* __restrict__ rbias)
{
  __shared__ float tl[8];
  const int pair = threadIdx.x >> 5, l = threadIdx.x & 31;
  const int b = pair >> 1, j = pair & 1;
  float s = 0.f;
  for (int i = l; i < DD; i += 32) s += pooled[b * DD + i] * Wt[i * 2 + j];
  #pragma unroll
  for (int o = 1; o < 32; o <<= 1) s += __shfl_xor(s, o, 64);
  if (l == 0) tl[pair] = s + bt[j];
  __syncthreads();
  if (threadIdx.x < 16) {
    const int bb = threadIdx.x >> 2, e = threadIdx.x & 3;
    rbias[threadIdx.x] = tl[bb * 2 + (e & 1)];
  }
}

// fast gelu(tanh)
__device__ __forceinline__ float gelu_tanh(float x) {
  const float u = 0.7978845608028654f * (x + 0.044715f * x * x * x);
  const float e = __expf(2.f * u);
  const float t = 1.f - 2.f / (e + 1.f);
  return 0.5f * x * (1.f + t);
}

// ---------- 128x128 bf16 MFMA GEMM (dense modes) ----------
// MODE 0: QKV — Q/K cols -> Cbf (qkv layout), V cols (>=1536) -> Vt transposed
// MODE 1: Cf = aux1 + acc (residual)
template <int MODE>
__global__ __launch_bounds__(256) void gemm128_kernel(
    const bf16* __restrict__ A, const bf16* __restrict__ Bt,
    bf16* __restrict__ Cbf, float* __restrict__ Cf,
    int N, int K, int NT, int GX,
    const float* __restrict__ aux1, bf16* __restrict__ Vt)
{
  __shared__ __align__(16) bf16 As[2][128 * 32];
  __shared__ __align__(16) bf16 Bs[2][128 * 32];

  const int nwg = gridDim.x;
  const int orig = blockIdx.x;
  const int q = nwg >> 3, r = nwg & 7;
  const int xcd = orig & 7, sidx = orig >> 3;
  const int wgid = (xcd < r ? xcd * (q + 1) : r * (q + 1) + (xcd - r) * q) + sidx;

  const int n0 = (wgid % GX) * 128;
  const int m0 = (wgid / GX) * 128;

  const int tid = threadIdx.x;
  const int lane = tid & 63, wv = tid >> 6;
  const int wr = wv >> 1, wc = wv & 1;
  const int lrow = lane & 15, lk = lane >> 4;
  const int lr = lrow, lg = lk;
  const int srow = lane >> 2;
  const int csw = (((lane & 3) ^ ((srow >> 1) & 3)) * 8);

  const bf16* arow[2];
  const bf16* brow[2];
  #pragma unroll
  for (int u = 0; u < 2; u++) {
    const int rbr = u * 64 + wv * 16 + srow;
    arow[u] = A + (long)(m0 + rbr) * K;
    brow[u] = Bt + (long)(n0 + rbr) * K;
  }

  f32x4 acc[4][4] = {};

#define STAGE(T, BUF)                                                   \
  {                                                                     \
    const int k0s = (T) * 32;                                           \
    _Pragma("unroll")                                                   \
    for (int u = 0; u < 2; u++) {                                       \
      const int rb = u * 64 + wv * 16;                                  \
      gld16(arow[u] + k0s + csw, &As[BUF][rb * 32]);                    \
      gld16(brow[u] + k0s + csw, &Bs[BUF][rb * 32]);                    \
    }                                                                   \
  }

  STAGE(0, 0)
  __syncthreads();

  for (int t = 0; t < NT; t++) {
    const int buf = t & 1;
    if (t + 1 < NT) STAGE(t + 1, buf ^ 1)

    bf16x8 af[4], bfr[4];
    #pragma unroll
    for (int i = 0; i < 4; i++) {
      const int ra = wr * 64 + i * 16 + lrow;
      const int rbw = wc * 64 + i * 16 + lrow;
      af[i]  = *(const bf16x8*)(&As[buf][ra * 32 + ((lk ^ ((ra >> 1) & 3)) * 8)]);
      bfr[i] = *(const bf16x8*)(&Bs[buf][rbw * 32 + ((lk ^ ((rbw >> 1) & 3)) * 8)]);
    }
    #pragma unroll
    for (int i = 0; i < 4; i++)
      #pragma unroll
      for (int j = 0; j < 4; j++)
        acc[i][j] = __builtin_amdgcn_mfma_f32_16x16x32_bf16(bfr[j], af[i], acc[i][j], 0, 0, 0);
    __syncthreads();
  }
#undef STAGE

  #pragma unroll
  for (int i = 0; i < 4; i++) {
    const int rloc = wr * 64 + i * 16 + lr;
    #pragma unroll
    for (int j = 0; j < 4; j++) {
      const int col = n0 + wc * 64 + j * 16 + lg * 4;
      const f32x4 v = acc[i][j];
      if (MODE == 0) {
        const int row = m0 + rloc;               // token index
        if (col < 1536) {
          short4 pk = make_short4(f2sb(v[0]), f2sb(v[1]), f2sb(v[2]), f2sb(v[3]));
          *(short4*)(&Cbf[(long)row * N + col]) = pk;
        } else {
          // V: write transposed into vt[(b*12+h)*64+d][s]
          const int c = col - 1536;              // h*64 + d, d 4-aligned
          const int bh64 = (row >> 10) * 768 + c;
          const int s = row & 1023;
          short* vp = (short*)Vt + (long)bh64 * 1024 + s;
          #pragma unroll
          for (int dd = 0; dd < 4; dd++)
            vp[(long)dd * 1024] = f2sb(v[dd]);
        }
      } else {
        const long idx = (long)(m0 + rloc) * N + col;
        const f32x4 xv = *(const f32x4*)(&aux1[idx]);
        f32x4 o = xv + v;
        *(f32x4*)(&Cf[idx]) = o;
      }
    }
  }
}

// ---------- 256x256 MoE GEMM, 8 waves, BK=64, 4-phase counted-vmcnt --------
// Barrier audit (r17): B-frags of Bl[buf] are read ONLY in phase 0, sealed by
// each wave's lgkmcnt(0) before the phase-0 barrier; SGB(kt+2,buf) writes are
// issued only after that barrier -> mid-tile barriers (phases 1,2) removed.
// Barriers remain at end of phase 0 and phase 3 (tile boundary + vmcnt(4)).
// MODE 2: segmented up (gathered A, gelu epilogue)
// MODE 3: segmented down split-K x2 (partial slabs)
template <int MODE>
__global__ __launch_bounds__(512, 1) void gemm256p_kernel(
    const bf16* __restrict__ A, const bf16* __restrict__ Bt,
    bf16* __restrict__ Cbf,
    int N, int K, int NT, int GX,
    const float* __restrict__ aux1, const float* __restrict__ gates,
    const int* __restrict__ tokl, const int* __restrict__ cnt_es,
    bf16* __restrict__ yB)
{
  __shared__ __align__(16) bf16 Al[2][256 * 64];
  __shared__ __align__(16) bf16 Bl[2][256 * 64];

  const int nwg = gridDim.x;
  const int orig = blockIdx.x;
  const int q = nwg >> 3, r = nwg & 7;
  const int xcd = orig & 7, sidx = orig >> 3;
  const int wgid = (xcd < r ? xcd * (q + 1) : r * (q + 1) + (xcd - r) * q) + sidx;

  const int n0 = (wgid % GX) * 256;
  int e = 0, g0 = 0, row0 = 0, nval = 0, kseg = 0, kh = 0;
  {
    int p = wgid / GX;
    if (MODE == 3) { kh = p & 1; p >>= 1; }
    int sacc = 0, pacc = 0, found = 0;
    #pragma unroll
    for (int k = 0; k < 8; k++) {
      const int c = cnt_es[k];
      const int pk = (c + 255) >> 8;
      if (!found && p < pacc + pk) {
        found = 1; kseg = k; e = k & 3;
        g0 = (p - pacc) * 256; row0 = sacc + g0; nval = c;
      }
      pacc += pk; sacc += c;
    }
    if (!found) return;
  }
  const int kofs = (MODE == 3) ? kh * 1536 : 0;

  const int tid = threadIdx.x;
  const int lane = tid & 63, wv = tid >> 6;
  const int wr = wv >> 2, wc = wv & 3;
  const int lrow = lane & 15, lk = lane >> 4;
  const int lr = lrow, lg = lk;

  const int strow = tid >> 3;
  const int stch = tid & 7;
  const int ssw = ((stch ^ (strow & 7)) * 8);

  const bf16* Be = Bt + (long)e * N * K;
  const bf16* pA[2][2];
  const bf16* pB[2][2];
  #pragma unroll
  for (int h = 0; h < 2; h++)
    #pragma unroll
    for (int c = 0; c < 2; c++) {
      const int rt = h * 128 + c * 64 + strow;
      if (MODE == 2) {
        const int g = g0 + rt;
        const int tk = (g < nval) ? tokl[kseg * 4096 + g] : tokl[kseg * 4096];
        pA[h][c] = A + (long)tk * K + kofs + ssw;
      } else {
        int rr = row0 + rt; if (rr > 8191) rr = 8191;
        pA[h][c] = A + (long)rr * K + kofs + ssw;
      }
      pB[h][c] = Be + (long)(n0 + rt) * K + kofs + ssw;
    }

#define LDSA(BUF, H, C) (&Al[BUF][(((H) * 128 + (C) * 64 + wv * 8)) * 64])
#define LDSB(BUF, H, C) (&Bl[BUF][(((H) * 128 + (C) * 64 + wv * 8)) * 64])
#define SGA(H, KT, BUF) { gld16(pA[H][0] + (KT) * 64, LDSA(BUF, H, 0)); \
                          gld16(pA[H][1] + (KT) * 64, LDSA(BUF, H, 1)); }
#define SGB(H, KT, BUF) { gld16(pB[H][0] + (KT) * 64, LDSB(BUF, H, 0)); \
                          gld16(pB[H][1] + (KT) * 64, LDSB(BUF, H, 1)); }

  int aoff[2], boff[2];
  #pragma unroll
  for (int ks = 0; ks < 2; ks++) {
    aoff[ks] = (wr * 128 + lrow) * 64 + (((ks * 4 + lk) ^ (lrow & 7)) * 8);
    boff[ks] = (wc * 64 + lrow) * 64 + (((ks * 4 + lk) ^ (lrow & 7)) * 8);
  }

  f32x4 acc[8][4] = {};

  SGA(0, 0, 0) SGA(1, 0, 0)
  SGB(0, 0, 0) SGB(1, 0, 0)
  SGB(0, 1, 1) SGB(1, 1, 1)
  asm volatile("s_waitcnt vmcnt(4)" ::: "memory");
  __builtin_amdgcn_s_barrier();
  __builtin_amdgcn_sched_barrier(0);

  bf16x8 bfr[4][2];

  for (int kt = 0; kt < NT; kt++) {
    const int buf = kt & 1;
    const int ao = buf * 16384, bo = buf * 16384;
    const bool stA = (kt + 1 < NT);
    const bool stB = (kt + 2 < NT);

    #pragma unroll
    for (int ph = 0; ph < 4; ph++) {
      if (ph == 0) { if (stA) SGA(0, kt + 1, buf ^ 1) }
      else if (ph == 1) { if (stA) SGA(1, kt + 1, buf ^ 1) }
      else if (ph == 2) { if (stB) SGB(0, kt + 2, buf) }
      else { if (stB) SGB(1, kt + 2, buf) }

      bf16x8 af[2][2];
      if (ph == 0) {
        #pragma unroll
        for (int j = 0; j < 4; j++)
          #pragma unroll
          for (int ks = 0; ks < 2; ks++)
            bfr[j][ks] = *(const bf16x8*)(&Bl[0][bo + boff[ks] + j * 1024]);
      }
      #pragma unroll
      for (int i2 = 0; i2 < 2; i2++)
        #pragma unroll
        for (int ks = 0; ks < 2; ks++)
          af[i2][ks] = *(const bf16x8*)(&Al[0][ao + aoff[ks] + (ph * 2 + i2) * 1024]);

      asm volatile("s_waitcnt lgkmcnt(0)" ::: "memory");
      __builtin_amdgcn_sched_barrier(0);
      __builtin_amdgcn_s_setprio(1);
      #pragma unroll
      for (int i2 = 0; i2 < 2; i2++)
        #pragma unroll
        for (int j = 0; j < 4; j++)
          #pragma unroll
          for (int ks = 0; ks < 2; ks++)
            acc[ph * 2 + i2][j] = __builtin_amdgcn_mfma_f32_16x16x32_bf16(
                bfr[j][ks], af[i2][ks], acc[ph * 2 + i2][j], 0, 0, 0);
      __builtin_amdgcn_s_setprio(0);
      __builtin_amdgcn_sched_barrier(0);

      if (ph == 3) {
        if (stB) asm volatile("s_waitcnt vmcnt(4)" ::: "memory");
        else     asm volatile("s_waitcnt vmcnt(0)" ::: "memory");
      }
      if (ph == 0 || ph == 3) {
        __builtin_amdgcn_s_barrier();
        __builtin_amdgcn_sched_barrier(0);
      }
    }
  }
#undef SGA
#undef SGB
#undef LDSA
#undef LDSB

  #pragma unroll
  for (int i = 0; i < 8; i++) {
    const int g = g0 + wr * 128 + i * 16 + lr;
    if (g < nval) {
      #pragma unroll
      for (int j = 0; j < 4; j++) {
        const int col = n0 + wc * 64 + j * 16 + lg * 4;
        const f32x4 v = acc[i][j];
        if (MODE == 2) {
          const float* b1e = aux1 + (long)e * N;
          const f32x4 bb = *(const f32x4*)(&b1e[col]);
          short4 pk = make_short4(f2sb(gelu_tanh(v[0] + bb[0])),
                                  f2sb(gelu_tanh(v[1] + bb[1])),
                                  f2sb(gelu_tanh(v[2] + bb[2])),
                                  f2sb(gelu_tanh(v[3] + bb[3])));
          *(short4*)(&Cbf[(long)(row0 - g0 + g) * N + col]) = pk;
        } else {
          const int tk = tokl[kseg * 4096 + g];
          const float gt = gates[tk * 4 + e];
          f32x4 vb = v;
          if (kh == 0) {
            const float* b2e = aux1 + (long)e * N;
            const f32x4 bb = *(const f32x4*)(&b2e[col]);
            vb = v + bb;
          }
          const int pidx = (kseg >> 2) * 2 + kh;
          bf16* yp = (pidx < 3) ? Cbf + (long)pidx * 3145728 : yB;
          short4 pk = make_short4(f2sb(gt * vb[0]), f2sb(gt * vb[1]),
                                  f2sb(gt * vb[2]), f2sb(gt * vb[3]));
          *(short4*)(&yp[(long)tk * 768 + col]) = pk;
        }
      }
    }
  }
}

// ---------- fuse: out += y0+y1+y2+y3 (bf16 partials) ----------
__global__ __launch_bounds__(256) void fuse_kernel(
    const bf16* __restrict__ yA, const bf16* __restrict__ yB,
    float* __restrict__ out)
{
  const long i = ((long)blockIdx.x * 256 + threadIdx.x) * 4;
  const short4 a = *(const short4*)((const short*)yA + i);
  const short4 b = *(const short4*)((const short*)yA + 3145728 + i);
  const short4 c = *(const short4*)((const short*)yA + 6291456 + i);
  const short4 d = *(const short4*)((const short*)yB + i);
  f32x4 o = *(f32x4*)(&out[i]);
  o[0] += sb2f(a.x) + sb2f(b.x) + sb2f(c.x) + sb2f(d.x);
  o[1] += sb2f(a.y) + sb2f(b.y) + sb2f(c.y) + sb2f(d.y);
  o[2] += sb2f(a.z) + sb2f(b.z) + sb2f(c.z) + sb2f(d.z);
  o[3] += sb2f(a.w) + sb2f(b.w) + sb2f(c.w) + sb2f(d.w);
  *(f32x4*)(&out[i]) = o;
}

// ---------- MFMA flash attention: 4 waves x 16 q-rows (r14-proven form) ----
__global__ __launch_bounds__(256) void attn_kernel(
    const bf16* __restrict__ qkv, const bf16* __restrict__ vt,
    bf16* __restrict__ ctx)
{
  __shared__ __align__(16) short Qs[64 * 64];
  __shared__ __align__(16) short Ks[64 * 64];
  __shared__ __align__(16) short Vts[64 * 64];
  __shared__ __align__(16) short Ps[4][16 * 64];

  const int qt = blockIdx.x;
  const int bh = blockIdx.y;
  const int b = bh / HH, h = bh % HH;
  const int tid = threadIdx.x, lane = tid & 63, w = tid >> 6;
  const int lr = lane & 15, lg = lane >> 4;

  const short* qg = (const short*)qkv + ((long)(b * SS + qt * 64)) * 2304 + h * 64;
  #pragma unroll
  for (int i = 0; i < 2; i++) {
    const int idx = i * 256 + tid;
    const int r = idx >> 3, c8 = idx & 7;
    bf16x8 v = *(const bf16x8*)(qg + (long)r * 2304 + c8 * 8);
    bf16x8 o;
    #pragma unroll
    for (int j = 0; j < 8; j++) o[j] = f2sb(sb2f(v[j]) * 0.125f);
    *(bf16x8*)(&Qs[r * 64 + ((c8 ^ (r & 7)) * 8)]) = o;
  }
  __syncthreads();

  bf16x8 aq[2];
  {
    const int r = w * 16 + lr;
    aq[0] = *(const bf16x8*)(&Qs[r * 64 + (((lg + 0) ^ (r & 7)) * 8)]);
    aq[1] = *(const bf16x8*)(&Qs[r * 64 + (((lg + 4) ^ (r & 7)) * 8)]);
  }

  float m_run[4], l_run[4];
  f32x4 oacc[4];
  #pragma unroll
  for (int r = 0; r < 4; r++) { m_run[r] = -1e30f; l_run[r] = 0.f; }
  #pragma unroll
  for (int dt = 0; dt < 4; dt++) oacc[dt] = (f32x4){0.f, 0.f, 0.f, 0.f};

  const short* kg = (const short*)qkv + ((long)(b * SS)) * 2304 + 768 + h * 64;
  const short* vg = (const short*)vt + ((long)bh * 64) * SS;
  const int sr = lane >> 3, sc = lane & 7;

  for (int kt = 0; kt < 16; kt++) {
    __syncthreads();
    #pragma unroll
    for (int c = 0; c < 2; c++) {
      const int rb = c * 32 + w * 8;
      const int row = rb + sr;
      const int ch = sc ^ (row & 7);
      gld16(kg + ((long)(kt * 64 + row)) * 2304 + ch * 8, &Ks[rb * 64]);
      gld16(vg + ((long)row) * SS + kt * 64 + ch * 8, &Vts[rb * 64]);
    }
    __syncthreads();

    f32x4 s[4];
    #pragma unroll
    for (int jt = 0; jt < 4; jt++) {
      const int r = jt * 16 + lr;
      bf16x8 bk0 = *(const bf16x8*)(&Ks[r * 64 + (((lg + 0) ^ (r & 7)) * 8)]);
      bf16x8 bk1 = *(const bf16x8*)(&Ks[r * 64 + (((lg + 4) ^ (r & 7)) * 8)]);
      f32x4 a = {};
      a = __builtin_amdgcn_mfma_f32_16x16x32_bf16(aq[0], bk0, a, 0, 0, 0);
      a = __builtin_amdgcn_mfma_f32_16x16x32_bf16(aq[1], bk1, a, 0, 0, 0);
      s[jt] = a;
    }

    #pragma unroll
    for (int r = 0; r < 4; r++) {
      float mt = fmaxf(fmaxf(s[0][r], s[1][r]), fmaxf(s[2][r], s[3][r]));
      mt = fmaxf(mt, __shfl_xor(mt, 1, 64));
      mt = fmaxf(mt, __shfl_xor(mt, 2, 64));
      mt = fmaxf(mt, __shfl_xor(mt, 4, 64));
      mt = fmaxf(mt, __shfl_xor(mt, 8, 64));
      const float mn = fmaxf(m_run[r], mt);
      const float sc0 = __expf(m_run[r] - mn);
      m_run[r] = mn;
      float p0 = __expf(s[0][r] - mn), p1 = __expf(s[1][r] - mn);
      float p2 = __expf(s[2][r] - mn), p3 = __expf(s[3][r] - mn);
      float rs = p0 + p1 + p2 + p3;
      rs += __shfl_xor(rs, 1, 64);
      rs += __shfl_xor(rs, 2, 64);
      rs += __shfl_xor(rs, 4, 64);
      rs += __shfl_xor(rs, 8, 64);
      l_run[r] = l_run[r] * sc0 + rs;
      #pragma unroll
      for (int dt = 0; dt < 4; dt++) oacc[dt][r] *= sc0;
      const int prow = lg * 4 + r;
      const int pswz = (prow & 7) << 3;
      Ps[w][prow * 64 + ((0 * 16 + lr) ^ pswz)] = f2sb(p0);
      Ps[w][prow * 64 + ((1 * 16 + lr) ^ pswz)] = f2sb(p1);
      Ps[w][prow * 64 + ((2 * 16 + lr) ^ pswz)] = f2sb(p2);
      Ps[w][prow * 64 + ((3 * 16 + lr) ^ pswz)] = f2sb(p3);
    }

    bf16x8 pa0 = *(const bf16x8*)(&Ps[w][lr * 64 + (((lg + 0) ^ (lr & 7)) << 3)]);
    bf16x8 pa1 = *(const bf16x8*)(&Ps[w][lr * 64 + (((lg + 4) ^ (lr & 7)) << 3)]);
    #pragma unroll
    for (int dt = 0; dt < 4; dt++) {
      const int r = dt * 16 + lr;
      bf16x8 bv0 = *(const bf16x8*)(&Vts[r * 64 + (((lg + 0) ^ (r & 7)) * 8)]);
      bf16x8 bv1 = *(const bf16x8*)(&Vts[r * 64 + (((lg + 4) ^ (r & 7)) * 8)]);
      oacc[dt] = __builtin_amdgcn_mfma_f32_16x16x32_bf16(pa0, bv0, oacc[dt], 0, 0, 0);
      oacc[dt] = __builtin_amdgcn_mfma_f32_16x16x32_bf16(pa1, bv1, oacc[dt], 0, 0, 0);
    }
  }

  #pragma unroll
  for (int r = 0; r < 4; r++) {
    const float inv = 1.f / l_run[r];
    const long row = (long)(b * SS + qt * 64 + w * 16 + lg * 4 + r);
    #pragma unroll
    for (int dt = 0; dt < 4; dt++)
      ctx[row * DD + h * 64 + dt * 16 + lr] = f2bf(oacc[dt][r] * inv);
  }
}

// ---------- LN2 + gate fused ----------
__global__ __launch_bounds__(256) void lngate_kernel(
    const float* __restrict__ x2, const float* __restrict__ g,
    const float* __restrict__ bln, const float* __restrict__ Wg,
    const float* __restrict__ rbias, bf16* __restrict__ h2,
    float* __restrict__ gates)
{
  const int t = blockIdx.x * 4 + (threadIdx.x >> 6);
  const int lane = threadIdx.x & 63;
  const int b = t >> 10;
  const float* xr = x2 + (long)t * DD;
  float v[12];
  float s = 0.f;
  #pragma unroll
  for (int i = 0; i < 12; i++) { v[i] = xr[lane + i * 64]; s += v[i]; }
  #pragma unroll
  for (int o = 1; o < 64; o <<= 1) s += __shfl_xor(s, o, 64);
  const float mu = s * (1.f / DD);
  float vs = 0.f;
  #pragma unroll
  for (int i = 0; i < 12; i++) { const float d = v[i] - mu; vs += d * d; }
  #pragma unroll
  for (int o = 1; o < 64; o <<= 1) vs += __shfl_xor(vs, o, 64);
  const float rstd = rsqrtf(vs * (1.f / DD) + 1e-5f);
  bf16* orow = h2 + (long)t * DD;
  float a0 = 0.f, a1 = 0.f, a2 = 0.f, a3 = 0.f;
  #pragma unroll
  for (int i = 0; i < 12; i++) {
    const int d = lane + i * 64;
    const float hv = (v[i] - mu) * rstd * g[d] + bln[d];
    orow[d] = f2bf(hv);
    const f32x4 w = *(const f32x4*)(&Wg[d * 4]);
    a0 += hv * w.x; a1 += hv * w.y; a2 += hv * w.z; a3 += hv * w.w;
  }
  #pragma unroll
  for (int o = 1; o < 64; o <<= 1) {
    a0 += __shfl_xor(a0, o, 64); a1 += __shfl_xor(a1, o, 64);
    a2 += __shfl_xor(a2, o, 64); a3 += __shfl_xor(a3, o, 64);
  }
  if (lane == 0) {
    float lg4[4] = { a0 + rbias[b * 4 + 0], a1 + rbias[b * 4 + 1],
                     a2 + rbias[b * 4 + 2], a3 + rbias[b * 4 + 3] };
    int i1 = 0;
    #pragma unroll
    for (int e = 1; e < 4; e++) if (lg4[e] > lg4[i1]) i1 = e;
    int i2 = -1;
    #pragma unroll
    for (int e = 0; e < 4; e++) if (e != i1 && (i2 < 0 || lg4[e] > lg4[i2])) i2 = e;
    const float e2 = __expf(lg4[i2] - lg4[i1]);
    const float den = 1.f + e2;
    float og[4] = {0.f, 0.f, 0.f, 0.f};
    og[i1] = 1.f / den;
    og[i2] = e2 / den;
    *(f32x4*)(&gates[t * 4]) = (f32x4){og[0], og[1], og[2], og[3]};
  }
}

// ---------- scan-based compaction: NO atomics, token-ordered, 1 block -----
__global__ __launch_bounds__(1024) void compact_kernel(
    const float* __restrict__ gates, int* __restrict__ tokl,
    int* __restrict__ cnt)
{
  __shared__ int wtot[8][16];
  const int tid = threadIdx.x;
  const int lane = tid & 63, w = tid >> 6;
  int sA[4], sB[4];
  int lc[8] = {0, 0, 0, 0, 0, 0, 0, 0};
  #pragma unroll
  for (int i = 0; i < 4; i++) {
    const int t = tid * 4 + i;
    const f32x4 g = *(const f32x4*)(&gates[t * 4]);
    int e1 = -1, e2 = -1;
    #pragma unroll
    for (int e = 0; e < 4; e++)
      if (g[e] > 0.f) { if (e1 < 0) e1 = e; else e2 = e; }
    sA[i] = e1; sB[i] = 4 + e2;
    lc[e1]++; lc[4 + e2]++;
  }
  int base[8];
  #pragma unroll
  for (int k = 0; k < 8; k++) {
    int v = lc[k];
    #pragma unroll
    for (int o = 1; o < 64; o <<= 1) {
      const int u = __shfl_up(v, o, 64);
      if (lane >= o) v += u;
    }
    base[k] = v - lc[k];
    if (lane == 63) wtot[k][w] = v;
  }
  __syncthreads();
  #pragma unroll
  for (int k = 0; k < 8; k++) {
    int b = 0;
    for (int ww = 0; ww < 16; ww++)
      if (ww < w) b += wtot[k][ww];
    base[k] += b;
  }
  #pragma unroll
  for (int i = 0; i < 4; i++) {
    const int t = tid * 4 + i;
    tokl[sA[i] * 4096 + base[sA[i]]] = t; base[sA[i]]++;
    tokl[sB[i] * 4096 + base[sB[i]]] = t; base[sB[i]]++;
  }
  if (tid < 8) {
    int s = 0;
    for (int ww = 0; ww < 16; ww++) s += wtot[tid][ww];
    cnt[tid] = s;
  }
}

extern "C" void kernel_launch(void* const* d_in, const int* in_sizes, int n_in,
                              void* d_out, int out_size, void* d_ws, size_t ws_size,
                              hipStream_t stream)
{
  (void)in_sizes; (void)n_in; (void)out_size; (void)ws_size;
  const float* x    = (const float*)d_in[0];
  const float* ln1g = (const float*)d_in[1];
  const float* ln1b = (const float*)d_in[2];
  const float* Wq   = (const float*)d_in[3];
  const float* Wk   = (const float*)d_in[4];
  const float* Wv   = (const float*)d_in[5];
  const float* Wo   = (const float*)d_in[6];
  const float* Wt   = (const float*)d_in[7];
  const float* bt   = (const float*)d_in[8];
  const float* ln2g = (const float*)d_in[9];
  const float* ln2b = (const float*)d_in[10];
  const float* Wg   = (const float*)d_in[11];
  const float* W1   = (const float*)d_in[12];
  const float* b1   = (const float*)d_in[13];
  const float* W2   = (const float*)d_in[14];
  const float* b2   = (const float*)d_in[15];
  float* out = (float*)d_out;

  char* ws = (char*)d_ws;
  bf16*  w1t    = (bf16*)(ws + 0);          // [4][3072][768] bf16 (dead after up)
  bf16*  w2t    = (bf16*)(ws + 18874368);   // [4][768][3072] bf16
  bf16*  h2     = (bf16*)(ws + 37748736);   // [4096][768] bf16 (dead after up)
  float* gates  = (float*)(ws + 44040192);  // [4096][4] f32
  int*   tokl   = (int*)(ws + 44105728);    // [8][4096]
  int*   cnt    = (int*)(ws + 44236800);    // [8]
  float* pooled = (float*)(ws + 44237056);  // [4][768]
  float* rbias  = (float*)(ws + 44249344);  // [4][4]
  bf16*  wqkv_t = (bf16*)(ws + 44249600);   // [2304][768] (Wo tacked after)
  bf16*  h1     = (bf16*)(ws + 48968192);   // [4096][768]
  bf16*  qkv    = (bf16*)(ws + 55259648);   // [4096][2304] (V third unused)
  bf16*  ctx    = (bf16*)(ws + 74134016);   // [4096][768]  (ends 80425472)
  bf16*  vt     = (bf16*)(ws + 80425472);   // [48][64][1024] (ends 86716928)
  bf16*  hid    = (bf16*)(ws + 44249600);   // [8192][3072] (dead zone, MoE time)
  bf16*  wo_t   = wqkv_t + 3 * 589824;
  bf16*  yA     = w1t;                      // 3 partial slabs
  bf16*  yB     = h2;                       // 4th partial slab
  float* pp     = (float*)qkv;              // pool partials (pre-QKV)

  transpose4_kernel<<<dim3(12, 12, 4), 256, 0, stream>>>(Wq, Wk, Wv, Wo, wqkv_t);
  transpose_cast_kernel<<<dim3(48, 12, 4), 256, 0, stream>>>(W1, w1t, 768, 3072, 2359296, 2359296);
  transpose_cast_kernel<<<dim3(12, 48, 4), 256, 0, stream>>>(W2, w2t, 3072, 768, 2359296, 2359296);

  ln1pool_kernel<<<1024, 256, 0, stream>>>(x, ln1g, ln1b, h1, pp);
  pool2_kernel<<<12, 256, 0, stream>>>(pp, pooled);
  route_kernel<<<1, 256, 0, stream>>>(pooled, Wt, bt, rbias);

  // QKV (V written transposed into vt directly)
  gemm128_kernel<0><<<32 * 18, 256, 0, stream>>>(h1, wqkv_t, qkv, nullptr,
                                                 2304, 768, 24, 18, nullptr, vt);
  attn_kernel<<<dim3(16, 48), 256, 0, stream>>>(qkv, vt, ctx);
  gemm128_kernel<1><<<32 * 6, 256, 0, stream>>>(ctx, wo_t, nullptr, out,
                                                768, 768, 24, 6, x, nullptr);
  lngate_kernel<<<1024, 256, 0, stream>>>(out, ln2g, ln2b, Wg, rbias, h2, gates);
  compact_kernel<<<1, 1024, 0, stream>>>(gates, tokl, cnt);

  // up-proj: 256x256, BK=64, 4-phase counted-vmcnt pipeline (NT=12)
  gemm256p_kernel<2><<<40 * 12, 512, 0, stream>>>(h2, w1t, hid,
                                                  3072, 768, 12, 12,
                                                  b1, nullptr, tokl, cnt, nullptr);
  // down-proj: split-K x2, NT=24 per half
  gemm256p_kernel<3><<<40 * 2 * 3, 512, 0, stream>>>(hid, w2t, yA,
                                                     768, 3072, 24, 3,
                                                     b2, gates, tokl, cnt, yB);
  fuse_kernel<<<3072, 256, 0, stream>>>(yA, yB, out);
}